// Round 1
// baseline (269.459 us; speedup 1.0000x reference)
//
#include <hip/hip_runtime.h>
#include <stdint.h>

// 3-layer GCN, gather-only aggregation off a per-node CSR.
// R16 = R15 locked configuration + ONE isolated change: k_bucket_csr now
// stages the per-bucket scatter in LDS, insertion-sorts each node's neighbor
// segment ASCENDING BY SRC, and copies out linearly (coalesced csr writes).
// Sorted lists make the co-resident gather wave in k_agg2_l1/k_agg30/k_agg1
// sweep the source tables front-to-back in loose lockstep -> L2 captures the
// x16 reuse of each 64B p2 row instead of spilling 165MB to L3/HBM.
// Everything else is byte-identical to the proven best (243.7us).
//  k_bin: CHUNK 6400, fused hist+LDS-sort+linear copy-out, shuffle scan,
//         edge list consumed in pairs (int2/longlong2 vector loads).
//  k_bucket_csr: 1024 thr, shuffle scan, LDS stage + per-node src-sort.
//  k_agg2_l1 / k_agg30 / k_layer2 / k_agg1: x8-unrolled cached gathers,
//  fp64 accumulators (order-independent), bf16 64B rows for dim-30.
// Packed edge = (src<<9)|(dst&511), src < 2^18.

#define CAP 9216    // bucket region capacity; mean 8184, sigma 90 -> +11 sigma
#define CHUNK 6400  // edges per k_bin block

__device__ __forceinline__ unsigned short f2bf(float f) {  // RNE, no NaN inputs
    unsigned u = __float_as_uint(f);
    unsigned r = ((u >> 16) & 1u) + 0x7FFFu;
    return (unsigned short)((u + r) >> 16);
}
__device__ __forceinline__ float bf2f(unsigned short h) {
    return __uint_as_float((unsigned)h << 16);
}

// Per-block int64-vs-int32 detect: int64 edge values < 2^18 => all high
// words zero; int32 data at those offsets is src values, ~surely nonzero.
__device__ __forceinline__ int detect64(const unsigned* ei, int* s_nz, int t) {
    unsigned v = ei[2 * (t & 255) + 1];
    if (v != 0) atomicAdd(s_nz, 1);
    __syncthreads();
    return (*s_nz == 0);
}

// Fused binning with local counting sort and coalesced copy-out. 512 thr.
// Edge list consumed in PAIRS via vector loads.
__global__ __launch_bounds__(512) void k_bin(const void* ei, long long E,
                                             int* gcnt, unsigned* binned, int B) {
    __shared__ int cursor[512];
    __shared__ int delta[512];
    __shared__ int wsum[8];
    __shared__ int s_total;
    __shared__ unsigned sv[CHUNK];
    __shared__ unsigned short sb[CHUNK];
    __shared__ int s_nz;
    int t = threadIdx.x, blk = blockIdx.x;
    if (t == 0) s_nz = 0;
    cursor[t] = 0;
    __syncthreads();
    int f = detect64((const unsigned*)ei, &s_nz, t);
    long long s = (long long)blk * CHUNK, e = min(E, s + CHUNK);
    // ---- histogram (pairs) ----
    if (f) {
        const long long* p = (const long long*)ei;
        long long i = s + 2 * t;
        for (; i + 1 < e; i += 1024) {
            longlong2 d = *(const longlong2*)(p + E + i);
            atomicAdd(&cursor[((int)d.x) >> 9], 1);
            atomicAdd(&cursor[((int)d.y) >> 9], 1);
        }
        if (i < e) atomicAdd(&cursor[((int)p[E + i]) >> 9], 1);
    } else {
        const int* p = (const int*)ei;
        long long i = s + 2 * t;
        for (; i + 1 < e; i += 1024) {
            int2 d = *(const int2*)(p + E + i);
            atomicAdd(&cursor[d.x >> 9], 1);
            atomicAdd(&cursor[d.y >> 9], 1);
        }
        if (i < e) atomicAdd(&cursor[p[E + i] >> 9], 1);
    }
    __syncthreads();
    // exclusive scan over 512 counts: wave shuffle scan + cross-wave offsets
    int c = cursor[t];
    int lane = t & 63, wid = t >> 6;
    int inc = c;
#pragma unroll
    for (int off = 1; off < 64; off <<= 1) {
        int up = __shfl_up(inc, off, 64);
        if (lane >= off) inc += up;
    }
    if (lane == 63) wsum[wid] = inc;
    __syncthreads();
    int base = 0;
    for (int k = 0; k < wid; k++) base += wsum[k];
    int ex = base + inc - c;
    if (t == 511) s_total = ex + c;
    int claim = c ? atomicAdd(&gcnt[t], c) : 0;
    delta[t] = t * CAP + claim - ex;
    cursor[t] = ex;
    __syncthreads();
    // ---- scatter into LDS (pairs), remember bucket id ----
    if (f) {
        const long long* p = (const long long*)ei;
        long long i = s + 2 * t;
        for (; i + 1 < e; i += 1024) {
            longlong2 sp = *(const longlong2*)(p + i);
            longlong2 dp = *(const longlong2*)(p + E + i);
            int b0 = ((int)dp.x) >> 9, b1 = ((int)dp.y) >> 9;
            int p0 = atomicAdd(&cursor[b0], 1);
            sv[p0] = ((unsigned)(int)sp.x << 9) | (unsigned)((int)dp.x & 511);
            sb[p0] = (unsigned short)b0;
            int p1v = atomicAdd(&cursor[b1], 1);
            sv[p1v] = ((unsigned)(int)sp.y << 9) | (unsigned)((int)dp.y & 511);
            sb[p1v] = (unsigned short)b1;
        }
        if (i < e) {
            int sval = (int)p[i], dv = (int)p[E + i];
            int b = dv >> 9;
            int pos = atomicAdd(&cursor[b], 1);
            sv[pos] = ((unsigned)sval << 9) | (unsigned)(dv & 511);
            sb[pos] = (unsigned short)b;
        }
    } else {
        const int* p = (const int*)ei;
        long long i = s + 2 * t;
        for (; i + 1 < e; i += 1024) {
            int2 sp = *(const int2*)(p + i);
            int2 dp = *(const int2*)(p + E + i);
            int b0 = dp.x >> 9, b1 = dp.y >> 9;
            int p0 = atomicAdd(&cursor[b0], 1);
            sv[p0] = ((unsigned)sp.x << 9) | (unsigned)(dp.x & 511);
            sb[p0] = (unsigned short)b0;
            int p1v = atomicAdd(&cursor[b1], 1);
            sv[p1v] = ((unsigned)sp.y << 9) | (unsigned)(dp.y & 511);
            sb[p1v] = (unsigned short)b1;
        }
        if (i < e) {
            int sval = p[i], dv = p[E + i];
            int b = dv >> 9;
            int pos = atomicAdd(&cursor[b], 1);
            sv[pos] = ((unsigned)sval << 9) | (unsigned)(dv & 511);
            sb[pos] = (unsigned short)b;
        }
    }
    __syncthreads();
    // linear copy-out (consecutive threads -> consecutive addresses)
    int total = s_total;
    for (int i = t; i < total; i += 512)
        binned[delta[sb[i]] + i] = sv[i];
}

// Per-bucket counting sort by local node. 1024 threads; shuffle scan over
// 512 counters. R16: scatter is staged in LDS, each node's segment is
// insertion-sorted ASCENDING BY SRC (one thread per node, ~16 elements),
// then copied out linearly -> coalesced csr writes + sweep-friendly gather
// order for the three aggregation kernels. Also iptr2, dinv, p1 = x*dinv.
__global__ __launch_bounds__(1024) void k_bucket_csr(
        const unsigned* binned, const int* gcnt, const float* x, int2* iptr2,
        float* dinv, float2* p1, int* csr, int n) {
    __shared__ int cur[512];
    __shared__ int seg[512];
    __shared__ int wsum[16];
    __shared__ int stage[CAP];
    int t = threadIdx.x, b = blockIdx.x;
    if (t < 512) cur[t] = 0;
    __syncthreads();
    int cnt = gcnt[b];
    const unsigned* bp = binned + (size_t)b * CAP;
    for (int i = t; i < cnt; i += 1024)
        atomicAdd(&cur[bp[i] & 511u], 1);
    __syncthreads();
    int c = (t < 512) ? cur[t] : 0;
    int lane = t & 63, wid = t >> 6;
    int inc = c;
#pragma unroll
    for (int off = 1; off < 64; off <<= 1) {
        int up = __shfl_up(inc, off, 64);
        if (lane >= off) inc += up;
    }
    if (lane == 63) wsum[wid] = inc;
    __syncthreads();
    int base = 0;
    for (int k = 0; k < wid; k++) base += wsum[k];
    int ex = base + inc - c;
    int gbase = b * CAP;
    if (t < 512) {
        seg[t] = ex;
        cur[t] = ex;  // LOCAL cursor into the LDS stage
        int node = b * 512 + t;
        if (node < n) {
            iptr2[node] = make_int2(gbase + ex, gbase + ex + c);
            float dg = (float)(c + 1);  // +1 self loop
            float r = rsqrtf(dg);
            r = r * (1.5f - 0.5f * dg * r * r);  // Newton refine
            dinv[node] = r;
            p1[node] = make_float2(x[2 * node] * r, x[2 * node + 1] * r);
        }
    }
    __syncthreads();
    for (int i = t; i < cnt; i += 1024) {
        unsigned p = bp[i];
        int pos = atomicAdd(&cur[p & 511u], 1);
        stage[pos] = (int)(p >> 9);
    }
    __syncthreads();
    // per-node insertion sort (ascending src); segments are ~16 elements
    if (t < 512) {
        int s0 = seg[t], e0 = cur[t];
        for (int i = s0 + 1; i < e0; i++) {
            int key = stage[i];
            int j = i - 1;
            while (j >= s0 && stage[j] > key) {
                stage[j + 1] = stage[j];
                j--;
            }
            stage[j + 1] = key;
        }
    }
    __syncthreads();
    // linear copy-out (coalesced)
    for (int i = t; i < cnt; i += 1024)
        csr[gbase + i] = stage[i];
}

// Fused: aggx = A_hat x (dim2, x8 unroll, fp64 acc);
// p2 = bf16(relu(aggx@W1+b1)*dinv), 64B rows (32 ushorts, 2 zero pads).
__global__ void k_agg2_l1(const float2* p1, const int2* iptr2, const int* csr,
                          const float* dinv, const float* W1, const float* b1,
                          float2* aggx, unsigned short* p2, int n) {
    int v = blockIdx.x * 256 + threadIdx.x;
    if (v >= n) return;
    float2 a0 = p1[v];
    double dax = a0.x, day = a0.y;
    int2 se = iptr2[v];
    int s = se.x, e = se.y;
    int i = s;
    for (; i + 7 < e; i += 8) {
        int u0 = csr[i], u1 = csr[i + 1], u2 = csr[i + 2], u3 = csr[i + 3];
        int u4 = csr[i + 4], u5 = csr[i + 5], u6 = csr[i + 6], u7 = csr[i + 7];
        float2 q0 = p1[u0], q1 = p1[u1], q2 = p1[u2], q3 = p1[u3];
        float2 q4 = p1[u4], q5 = p1[u5], q6 = p1[u6], q7 = p1[u7];
        dax += ((double)q0.x + q1.x) + ((double)q2.x + q3.x) +
               ((double)q4.x + q5.x) + ((double)q6.x + q7.x);
        day += ((double)q0.y + q1.y) + ((double)q2.y + q3.y) +
               ((double)q4.y + q5.y) + ((double)q6.y + q7.y);
    }
    for (; i < e; i++) {
        float2 q = p1[csr[i]];
        dax += (double)q.x; day += (double)q.y;
    }
    float r = dinv[v];
    float ax = (float)(dax * (double)r), ay = (float)(day * (double)r);
    aggx[v] = make_float2(ax, ay);
    __align__(16) unsigned short ob[32];
#pragma unroll
    for (int j = 0; j < 30; j++)
        ob[j] = f2bf(fmaxf(fmaf(ax, W1[j], fmaf(ay, W1[30 + j], b1[j])), 0.f) * r);
    ob[30] = 0; ob[31] = 0;
    uint4* d4 = (uint4*)(p2 + (size_t)v * 32);
    const uint4* s4 = (const uint4*)ob;
#pragma unroll
    for (int k = 0; k < 4; k++) d4[k] = s4[k];
}

// Dim-30 aggregation: 8-lane group per node, each lane a uint2 (4 bf16,
// 64B/row/group), x8-unrolled independent gathers, fp64 accumulators.
__global__ void k_agg30(const uint2* p2u, const int2* iptr2,
                        const int* csr, const float* dinv,
                        uint2* agghu, int n) {
    int t = threadIdx.x;
    int g = blockIdx.x * 32 + (t >> 3);
    int l = t & 7;
    if (g >= n) return;
    uint2 w = p2u[(size_t)g * 8 + l];  // self loop (pads zero)
    double a0 = (double)bf2f((unsigned short)(w.x & 0xFFFFu));
    double a1 = (double)bf2f((unsigned short)(w.x >> 16));
    double a2 = (double)bf2f((unsigned short)(w.y & 0xFFFFu));
    double a3 = (double)bf2f((unsigned short)(w.y >> 16));
    int2 se = iptr2[g];
    int s = se.x, e = se.y;
    int i = s;
    for (; i + 7 < e; i += 8) {
        int u0 = csr[i], u1 = csr[i + 1], u2 = csr[i + 2], u3 = csr[i + 3];
        int u4 = csr[i + 4], u5 = csr[i + 5], u6 = csr[i + 6], u7 = csr[i + 7];
        uint2 w0 = p2u[(size_t)u0 * 8 + l];
        uint2 w1 = p2u[(size_t)u1 * 8 + l];
        uint2 w2 = p2u[(size_t)u2 * 8 + l];
        uint2 w3 = p2u[(size_t)u3 * 8 + l];
        uint2 w4 = p2u[(size_t)u4 * 8 + l];
        uint2 w5 = p2u[(size_t)u5 * 8 + l];
        uint2 w6 = p2u[(size_t)u6 * 8 + l];
        uint2 w7 = p2u[(size_t)u7 * 8 + l];
        a0 += ((double)bf2f((unsigned short)(w0.x & 0xFFFFu)) + bf2f((unsigned short)(w1.x & 0xFFFFu))) +
              ((double)bf2f((unsigned short)(w2.x & 0xFFFFu)) + bf2f((unsigned short)(w3.x & 0xFFFFu))) +
              ((double)bf2f((unsigned short)(w4.x & 0xFFFFu)) + bf2f((unsigned short)(w5.x & 0xFFFFu))) +
              ((double)bf2f((unsigned short)(w6.x & 0xFFFFu)) + bf2f((unsigned short)(w7.x & 0xFFFFu)));
        a1 += ((double)bf2f((unsigned short)(w0.x >> 16)) + bf2f((unsigned short)(w1.x >> 16))) +
              ((double)bf2f((unsigned short)(w2.x >> 16)) + bf2f((unsigned short)(w3.x >> 16))) +
              ((double)bf2f((unsigned short)(w4.x >> 16)) + bf2f((unsigned short)(w5.x >> 16))) +
              ((double)bf2f((unsigned short)(w6.x >> 16)) + bf2f((unsigned short)(w7.x >> 16)));
        a2 += ((double)bf2f((unsigned short)(w0.y & 0xFFFFu)) + bf2f((unsigned short)(w1.y & 0xFFFFu))) +
              ((double)bf2f((unsigned short)(w2.y & 0xFFFFu)) + bf2f((unsigned short)(w3.y & 0xFFFFu))) +
              ((double)bf2f((unsigned short)(w4.y & 0xFFFFu)) + bf2f((unsigned short)(w5.y & 0xFFFFu))) +
              ((double)bf2f((unsigned short)(w6.y & 0xFFFFu)) + bf2f((unsigned short)(w7.y & 0xFFFFu)));
        a3 += ((double)bf2f((unsigned short)(w0.y >> 16)) + bf2f((unsigned short)(w1.y >> 16))) +
              ((double)bf2f((unsigned short)(w2.y >> 16)) + bf2f((unsigned short)(w3.y >> 16))) +
              ((double)bf2f((unsigned short)(w4.y >> 16)) + bf2f((unsigned short)(w5.y >> 16))) +
              ((double)bf2f((unsigned short)(w6.y >> 16)) + bf2f((unsigned short)(w7.y >> 16)));
    }
    for (; i < e; i++) {
        uint2 wv = p2u[(size_t)csr[i] * 8 + l];
        a0 += (double)bf2f((unsigned short)(wv.x & 0xFFFFu));
        a1 += (double)bf2f((unsigned short)(wv.x >> 16));
        a2 += (double)bf2f((unsigned short)(wv.y & 0xFFFFu));
        a3 += (double)bf2f((unsigned short)(wv.y >> 16));
    }
    double r = (double)dinv[g];
    uint2 o;
    o.x = (unsigned)f2bf((float)(a0 * r)) | ((unsigned)f2bf((float)(a1 * r)) << 16);
    o.y = (unsigned)f2bf((float)(a2 * r)) | ((unsigned)f2bf((float)(a3 * r)) << 16);
    agghu[(size_t)g * 8 + l] = o;  // pads (cols 30,31) are zero-sums -> stay 0
}

// h2 = relu((Ah1)W2[:30] + (Ax)W2[30:] + b2); p3 = ([h2,x]@W3) * dinv.
// Block stages its 256 bf16 aggh rows through LDS (stride-17 uints).
__global__ void k_layer2(const unsigned short* aggh, const float2* aggx,
                         const float* x, const float* W2, const float* W3,
                         const float* b2, const float* dinv, float* p3, int n) {
    __shared__ float W2s[32 * 30];
    __shared__ float W3s[32];
    __shared__ float b2s[30];
    __shared__ unsigned hsh[256 * 17];
    int t = threadIdx.x;
    for (int i = t; i < 960; i += 256) W2s[i] = W2[i];
    if (t < 32) W3s[t] = W3[t];
    if (t < 30) b2s[t] = b2[t];
    const unsigned* ag = (const unsigned*)aggh + (size_t)blockIdx.x * 256 * 16;
    int rows = min(256, n - blockIdx.x * 256);
    for (int i = t; i < rows * 16; i += 256) {
        int rr = i >> 4, cc = i & 15;
        hsh[rr * 17 + cc] = ag[i];
    }
    __syncthreads();
    int v = blockIdx.x * 256 + t;
    if (v >= n) return;
    float2 a = aggx[v];
    float acc[30];
#pragma unroll
    for (int j = 0; j < 30; j++)
        acc[j] = fmaf(a.x, W2s[30 * 30 + j], fmaf(a.y, W2s[31 * 30 + j], b2s[j]));
#pragma unroll
    for (int kk = 0; kk < 15; kk++) {  // 30 values = 15 uint pairs
        unsigned pr = hsh[t * 17 + kk];
        float h0 = bf2f((unsigned short)(pr & 0xFFFFu));
        float h1v = bf2f((unsigned short)(pr >> 16));
#pragma unroll
        for (int j = 0; j < 30; j++)
            acc[j] = fmaf(h0, W2s[(2 * kk) * 30 + j], acc[j]);
#pragma unroll
        for (int j = 0; j < 30; j++)
            acc[j] = fmaf(h1v, W2s[(2 * kk + 1) * 30 + j], acc[j]);
    }
    float s3 = 0.f;
#pragma unroll
    for (int j = 0; j < 30; j++) s3 = fmaf(fmaxf(acc[j], 0.f), W3s[j], s3);
    s3 = fmaf(x[2 * v], W3s[30], s3);
    s3 = fmaf(x[2 * v + 1], W3s[31], s3);
    p3[v] = s3 * dinv[v];
}

// out_v = dinv_v * (p3_v + sum p3_u) + b3   (dim 1, x8 unroll, fp64 acc)
__global__ void k_agg1(const float* p3, const int2* iptr2, const int* csr,
                       const float* dinv, const float* b3, float* out, int n) {
    int v = blockIdx.x * 256 + threadIdx.x;
    if (v >= n) return;
    double acc = (double)p3[v];
    int2 se = iptr2[v];
    int s = se.x, e = se.y;
    int i = s;
    for (; i + 7 < e; i += 8) {
        int u0 = csr[i], u1 = csr[i + 1], u2 = csr[i + 2], u3 = csr[i + 3];
        int u4 = csr[i + 4], u5 = csr[i + 5], u6 = csr[i + 6], u7 = csr[i + 7];
        float f0 = p3[u0], f1 = p3[u1], f2 = p3[u2], f3 = p3[u3];
        float f4 = p3[u4], f5 = p3[u5], f6 = p3[u6], f7 = p3[u7];
        acc += ((double)f0 + f1) + ((double)f2 + f3) +
               ((double)f4 + f5) + ((double)f6 + f7);
    }
    for (; i < e; i++) acc += (double)p3[csr[i]];
    out[v] = (float)(acc * (double)dinv[v] + (double)b3[0]);
}

extern "C" void kernel_launch(void* const* d_in, const int* in_sizes, int n_in,
                              void* d_out, int out_size, void* d_ws, size_t ws_size,
                              hipStream_t stream) {
    const float* x  = (const float*)d_in[0];
    const void*  ei = d_in[1];
    const float* W1 = (const float*)d_in[2];
    const float* b1 = (const float*)d_in[3];
    const float* W2 = (const float*)d_in[4];
    const float* b2 = (const float*)d_in[5];
    const float* W3 = (const float*)d_in[6];
    const float* b3 = (const float*)d_in[7];
    float* out = (float*)d_out;
    const int n = in_sizes[0] / 2;
    const long long E = in_sizes[1] / 2;
    const int B = (n + 511) / 512;  // dst buckets of 512 nodes (<=512 buckets)

    char* w = (char*)d_ws;
    auto alloc = [&](size_t b) { void* p = (void*)w; w += (b + 255) & ~(size_t)255; return p; };
    int*            gcnt   = (int*)alloc(512 * 4);
    unsigned*       binned = (unsigned*)alloc((size_t)B * CAP * 4);
    int*            csr    = (int*)alloc((size_t)B * CAP * 4);
    int2*           iptr2  = (int2*)alloc((size_t)n * 8);
    float*          dinv   = (float*)alloc((size_t)n * 4);
    float2*         p1     = (float2*)alloc((size_t)n * 8);
    float2*         aggx   = (float2*)alloc((size_t)n * 8);
    unsigned short* p2     = (unsigned short*)alloc((size_t)n * 32 * 2);
    unsigned short* aggh   = (unsigned short*)alloc((size_t)n * 32 * 2);
    float*          p3     = (float*)alloc((size_t)n * 4);

    int nblocks = (n + 255) / 256;
    int nbin = (int)((E + CHUNK - 1) / CHUNK);

    hipMemsetAsync(gcnt, 0, 512 * 4, stream);
    k_bin<<<nbin, 512, 0, stream>>>(ei, E, gcnt, binned, B);
    k_bucket_csr<<<B, 1024, 0, stream>>>(binned, gcnt, x, iptr2, dinv, p1, csr, n);
    k_agg2_l1<<<nblocks, 256, 0, stream>>>(p1, iptr2, csr, dinv, W1, b1, aggx, p2, n);
    k_agg30<<<(n + 31) / 32, 256, 0, stream>>>((const uint2*)p2, iptr2, csr, dinv,
                                               (uint2*)aggh, n);
    k_layer2<<<nblocks, 256, 0, stream>>>(aggh, aggx, x, W2, W3, b2, dinv, p3, n);
    k_agg1<<<nblocks, 256, 0, stream>>>(p3, iptr2, csr, dinv, b3, out, n);
}

// Round 2
// 250.560 us; speedup vs baseline: 1.0754x; 1.0754x over previous
//
#include <hip/hip_runtime.h>
#include <stdint.h>

// 3-layer GCN, gather-only aggregation off a per-node CSR.
// R17 = R16 with the per-node SORT ALGORITHM swapped: the serial insertion
// sort (dependent LDS chains, 3.4M bank-conflict cycles, +40us) is replaced
// by RANK-BASED counting sort: each edge independently counts how many keys
// in its segment precede it (ties broken by stage position) and scatters
// straight to its final csr slot. ~130 independent pipelined LDS reads per
// thread, broadcast-friendly (co-resident threads scan the same segment).
// csr content is identical to R16 (exact ascending-by-src per node), so the
// gather kernels keep their sorted-sweep L2 locality gains.
//  k_bin: CHUNK 6400, fused hist+LDS-sort+linear copy-out, shuffle scan,
//         edge list consumed in pairs (int2/longlong2 vector loads).
//  k_bucket_csr: 1024 thr, shuffle scan, LDS stage + rank-sort + scatter.
//  k_agg2_l1 / k_agg30 / k_layer2 / k_agg1: x8-unrolled cached gathers,
//  fp64 accumulators (order-independent), bf16 64B rows for dim-30.
// Packed edge = (src<<9)|(dst&511), src < 2^18.

#define CAP 9216    // bucket region capacity; mean 8184, sigma 90 -> +11 sigma
#define CHUNK 6400  // edges per k_bin block

__device__ __forceinline__ unsigned short f2bf(float f) {  // RNE, no NaN inputs
    unsigned u = __float_as_uint(f);
    unsigned r = ((u >> 16) & 1u) + 0x7FFFu;
    return (unsigned short)((u + r) >> 16);
}
__device__ __forceinline__ float bf2f(unsigned short h) {
    return __uint_as_float((unsigned)h << 16);
}

// Per-block int64-vs-int32 detect: int64 edge values < 2^18 => all high
// words zero; int32 data at those offsets is src values, ~surely nonzero.
__device__ __forceinline__ int detect64(const unsigned* ei, int* s_nz, int t) {
    unsigned v = ei[2 * (t & 255) + 1];
    if (v != 0) atomicAdd(s_nz, 1);
    __syncthreads();
    return (*s_nz == 0);
}

// Fused binning with local counting sort and coalesced copy-out. 512 thr.
// Edge list consumed in PAIRS via vector loads.
__global__ __launch_bounds__(512) void k_bin(const void* ei, long long E,
                                             int* gcnt, unsigned* binned, int B) {
    __shared__ int cursor[512];
    __shared__ int delta[512];
    __shared__ int wsum[8];
    __shared__ int s_total;
    __shared__ unsigned sv[CHUNK];
    __shared__ unsigned short sb[CHUNK];
    __shared__ int s_nz;
    int t = threadIdx.x, blk = blockIdx.x;
    if (t == 0) s_nz = 0;
    cursor[t] = 0;
    __syncthreads();
    int f = detect64((const unsigned*)ei, &s_nz, t);
    long long s = (long long)blk * CHUNK, e = min(E, s + CHUNK);
    // ---- histogram (pairs) ----
    if (f) {
        const long long* p = (const long long*)ei;
        long long i = s + 2 * t;
        for (; i + 1 < e; i += 1024) {
            longlong2 d = *(const longlong2*)(p + E + i);
            atomicAdd(&cursor[((int)d.x) >> 9], 1);
            atomicAdd(&cursor[((int)d.y) >> 9], 1);
        }
        if (i < e) atomicAdd(&cursor[((int)p[E + i]) >> 9], 1);
    } else {
        const int* p = (const int*)ei;
        long long i = s + 2 * t;
        for (; i + 1 < e; i += 1024) {
            int2 d = *(const int2*)(p + E + i);
            atomicAdd(&cursor[d.x >> 9], 1);
            atomicAdd(&cursor[d.y >> 9], 1);
        }
        if (i < e) atomicAdd(&cursor[p[E + i] >> 9], 1);
    }
    __syncthreads();
    // exclusive scan over 512 counts: wave shuffle scan + cross-wave offsets
    int c = cursor[t];
    int lane = t & 63, wid = t >> 6;
    int inc = c;
#pragma unroll
    for (int off = 1; off < 64; off <<= 1) {
        int up = __shfl_up(inc, off, 64);
        if (lane >= off) inc += up;
    }
    if (lane == 63) wsum[wid] = inc;
    __syncthreads();
    int base = 0;
    for (int k = 0; k < wid; k++) base += wsum[k];
    int ex = base + inc - c;
    if (t == 511) s_total = ex + c;
    int claim = c ? atomicAdd(&gcnt[t], c) : 0;
    delta[t] = t * CAP + claim - ex;
    cursor[t] = ex;
    __syncthreads();
    // ---- scatter into LDS (pairs), remember bucket id ----
    if (f) {
        const long long* p = (const long long*)ei;
        long long i = s + 2 * t;
        for (; i + 1 < e; i += 1024) {
            longlong2 sp = *(const longlong2*)(p + i);
            longlong2 dp = *(const longlong2*)(p + E + i);
            int b0 = ((int)dp.x) >> 9, b1 = ((int)dp.y) >> 9;
            int p0 = atomicAdd(&cursor[b0], 1);
            sv[p0] = ((unsigned)(int)sp.x << 9) | (unsigned)((int)dp.x & 511);
            sb[p0] = (unsigned short)b0;
            int p1v = atomicAdd(&cursor[b1], 1);
            sv[p1v] = ((unsigned)(int)sp.y << 9) | (unsigned)((int)dp.y & 511);
            sb[p1v] = (unsigned short)b1;
        }
        if (i < e) {
            int sval = (int)p[i], dv = (int)p[E + i];
            int b = dv >> 9;
            int pos = atomicAdd(&cursor[b], 1);
            sv[pos] = ((unsigned)sval << 9) | (unsigned)(dv & 511);
            sb[pos] = (unsigned short)b;
        }
    } else {
        const int* p = (const int*)ei;
        long long i = s + 2 * t;
        for (; i + 1 < e; i += 1024) {
            int2 sp = *(const int2*)(p + i);
            int2 dp = *(const int2*)(p + E + i);
            int b0 = dp.x >> 9, b1 = dp.y >> 9;
            int p0 = atomicAdd(&cursor[b0], 1);
            sv[p0] = ((unsigned)sp.x << 9) | (unsigned)(dp.x & 511);
            sb[p0] = (unsigned short)b0;
            int p1v = atomicAdd(&cursor[b1], 1);
            sv[p1v] = ((unsigned)sp.y << 9) | (unsigned)(dp.y & 511);
            sb[p1v] = (unsigned short)b1;
        }
        if (i < e) {
            int sval = p[i], dv = p[E + i];
            int b = dv >> 9;
            int pos = atomicAdd(&cursor[b], 1);
            sv[pos] = ((unsigned)sval << 9) | (unsigned)(dv & 511);
            sb[pos] = (unsigned short)b;
        }
    }
    __syncthreads();
    // linear copy-out (consecutive threads -> consecutive addresses)
    int total = s_total;
    for (int i = t; i < total; i += 512)
        binned[delta[sb[i]] + i] = sv[i];
}

// Per-bucket counting sort by local node. 1024 threads; shuffle scan over
// 512 counters. R17: scatter staged in LDS (value + 16-bit local node id),
// then each edge computes its in-segment RANK by scanning its node's segment
// (independent pipelined LDS reads; same-segment threads broadcast) and
// scatters directly to its final csr slot -> exact ascending-by-src lists
// with zero serial chains. Also iptr2, dinv, p1 = x*dinv.
__global__ __launch_bounds__(1024) void k_bucket_csr(
        const unsigned* binned, const int* gcnt, const float* x, int2* iptr2,
        float* dinv, float2* p1, int* csr, int n) {
    __shared__ int cur[512];
    __shared__ int seg[512];
    __shared__ int wsum[16];
    __shared__ int stage[CAP];
    __shared__ unsigned short snode[CAP];
    int t = threadIdx.x, b = blockIdx.x;
    if (t < 512) cur[t] = 0;
    __syncthreads();
    int cnt = gcnt[b];
    const unsigned* bp = binned + (size_t)b * CAP;
    for (int i = t; i < cnt; i += 1024)
        atomicAdd(&cur[bp[i] & 511u], 1);
    __syncthreads();
    int c = (t < 512) ? cur[t] : 0;
    int lane = t & 63, wid = t >> 6;
    int inc = c;
#pragma unroll
    for (int off = 1; off < 64; off <<= 1) {
        int up = __shfl_up(inc, off, 64);
        if (lane >= off) inc += up;
    }
    if (lane == 63) wsum[wid] = inc;
    __syncthreads();
    int base = 0;
    for (int k = 0; k < wid; k++) base += wsum[k];
    int ex = base + inc - c;
    int gbase = b * CAP;
    if (t < 512) {
        seg[t] = ex;
        cur[t] = ex;  // LOCAL cursor into the LDS stage
        int node = b * 512 + t;
        if (node < n) {
            iptr2[node] = make_int2(gbase + ex, gbase + ex + c);
            float dg = (float)(c + 1);  // +1 self loop
            float r = rsqrtf(dg);
            r = r * (1.5f - 0.5f * dg * r * r);  // Newton refine
            dinv[node] = r;
            p1[node] = make_float2(x[2 * node] * r, x[2 * node + 1] * r);
        }
    }
    __syncthreads();
    for (int i = t; i < cnt; i += 1024) {
        unsigned p = bp[i];
        int lnode = (int)(p & 511u);
        int pos = atomicAdd(&cur[lnode], 1);
        stage[pos] = (int)(p >> 9);
        snode[pos] = (unsigned short)lnode;
    }
    __syncthreads();
    // rank-based per-segment sort: each edge counts predecessors in its
    // segment (ties broken by stage position) -> unique final slot.
    // After the scatter loop, cur[node] == segment end.
    for (int i = t; i < cnt; i += 1024) {
        int key = stage[i];
        int nd = snode[i];
        int s0 = seg[nd], e0 = cur[nd];
        int r = s0;
        for (int j = s0; j < e0; j++) {
            int kj = stage[j];
            r += (int)((kj < key) | ((kj == key) & (j < i)));
        }
        csr[gbase + r] = key;
    }
}

// Fused: aggx = A_hat x (dim2, x8 unroll, fp64 acc);
// p2 = bf16(relu(aggx@W1+b1)*dinv), 64B rows (32 ushorts, 2 zero pads).
__global__ void k_agg2_l1(const float2* p1, const int2* iptr2, const int* csr,
                          const float* dinv, const float* W1, const float* b1,
                          float2* aggx, unsigned short* p2, int n) {
    int v = blockIdx.x * 256 + threadIdx.x;
    if (v >= n) return;
    float2 a0 = p1[v];
    double dax = a0.x, day = a0.y;
    int2 se = iptr2[v];
    int s = se.x, e = se.y;
    int i = s;
    for (; i + 7 < e; i += 8) {
        int u0 = csr[i], u1 = csr[i + 1], u2 = csr[i + 2], u3 = csr[i + 3];
        int u4 = csr[i + 4], u5 = csr[i + 5], u6 = csr[i + 6], u7 = csr[i + 7];
        float2 q0 = p1[u0], q1 = p1[u1], q2 = p1[u2], q3 = p1[u3];
        float2 q4 = p1[u4], q5 = p1[u5], q6 = p1[u6], q7 = p1[u7];
        dax += ((double)q0.x + q1.x) + ((double)q2.x + q3.x) +
               ((double)q4.x + q5.x) + ((double)q6.x + q7.x);
        day += ((double)q0.y + q1.y) + ((double)q2.y + q3.y) +
               ((double)q4.y + q5.y) + ((double)q6.y + q7.y);
    }
    for (; i < e; i++) {
        float2 q = p1[csr[i]];
        dax += (double)q.x; day += (double)q.y;
    }
    float r = dinv[v];
    float ax = (float)(dax * (double)r), ay = (float)(day * (double)r);
    aggx[v] = make_float2(ax, ay);
    __align__(16) unsigned short ob[32];
#pragma unroll
    for (int j = 0; j < 30; j++)
        ob[j] = f2bf(fmaxf(fmaf(ax, W1[j], fmaf(ay, W1[30 + j], b1[j])), 0.f) * r);
    ob[30] = 0; ob[31] = 0;
    uint4* d4 = (uint4*)(p2 + (size_t)v * 32);
    const uint4* s4 = (const uint4*)ob;
#pragma unroll
    for (int k = 0; k < 4; k++) d4[k] = s4[k];
}

// Dim-30 aggregation: 8-lane group per node, each lane a uint2 (4 bf16,
// 64B/row/group), x8-unrolled independent gathers, fp64 accumulators.
__global__ void k_agg30(const uint2* p2u, const int2* iptr2,
                        const int* csr, const float* dinv,
                        uint2* agghu, int n) {
    int t = threadIdx.x;
    int g = blockIdx.x * 32 + (t >> 3);
    int l = t & 7;
    if (g >= n) return;
    uint2 w = p2u[(size_t)g * 8 + l];  // self loop (pads zero)
    double a0 = (double)bf2f((unsigned short)(w.x & 0xFFFFu));
    double a1 = (double)bf2f((unsigned short)(w.x >> 16));
    double a2 = (double)bf2f((unsigned short)(w.y & 0xFFFFu));
    double a3 = (double)bf2f((unsigned short)(w.y >> 16));
    int2 se = iptr2[g];
    int s = se.x, e = se.y;
    int i = s;
    for (; i + 7 < e; i += 8) {
        int u0 = csr[i], u1 = csr[i + 1], u2 = csr[i + 2], u3 = csr[i + 3];
        int u4 = csr[i + 4], u5 = csr[i + 5], u6 = csr[i + 6], u7 = csr[i + 7];
        uint2 w0 = p2u[(size_t)u0 * 8 + l];
        uint2 w1 = p2u[(size_t)u1 * 8 + l];
        uint2 w2 = p2u[(size_t)u2 * 8 + l];
        uint2 w3 = p2u[(size_t)u3 * 8 + l];
        uint2 w4 = p2u[(size_t)u4 * 8 + l];
        uint2 w5 = p2u[(size_t)u5 * 8 + l];
        uint2 w6 = p2u[(size_t)u6 * 8 + l];
        uint2 w7 = p2u[(size_t)u7 * 8 + l];
        a0 += ((double)bf2f((unsigned short)(w0.x & 0xFFFFu)) + bf2f((unsigned short)(w1.x & 0xFFFFu))) +
              ((double)bf2f((unsigned short)(w2.x & 0xFFFFu)) + bf2f((unsigned short)(w3.x & 0xFFFFu))) +
              ((double)bf2f((unsigned short)(w4.x & 0xFFFFu)) + bf2f((unsigned short)(w5.x & 0xFFFFu))) +
              ((double)bf2f((unsigned short)(w6.x & 0xFFFFu)) + bf2f((unsigned short)(w7.x & 0xFFFFu)));
        a1 += ((double)bf2f((unsigned short)(w0.x >> 16)) + bf2f((unsigned short)(w1.x >> 16))) +
              ((double)bf2f((unsigned short)(w2.x >> 16)) + bf2f((unsigned short)(w3.x >> 16))) +
              ((double)bf2f((unsigned short)(w4.x >> 16)) + bf2f((unsigned short)(w5.x >> 16))) +
              ((double)bf2f((unsigned short)(w6.x >> 16)) + bf2f((unsigned short)(w7.x >> 16)));
        a2 += ((double)bf2f((unsigned short)(w0.y & 0xFFFFu)) + bf2f((unsigned short)(w1.y & 0xFFFFu))) +
              ((double)bf2f((unsigned short)(w2.y & 0xFFFFu)) + bf2f((unsigned short)(w3.y & 0xFFFFu))) +
              ((double)bf2f((unsigned short)(w4.y & 0xFFFFu)) + bf2f((unsigned short)(w5.y & 0xFFFFu))) +
              ((double)bf2f((unsigned short)(w6.y & 0xFFFFu)) + bf2f((unsigned short)(w7.y & 0xFFFFu)));
        a3 += ((double)bf2f((unsigned short)(w0.y >> 16)) + bf2f((unsigned short)(w1.y >> 16))) +
              ((double)bf2f((unsigned short)(w2.y >> 16)) + bf2f((unsigned short)(w3.y >> 16))) +
              ((double)bf2f((unsigned short)(w4.y >> 16)) + bf2f((unsigned short)(w5.y >> 16))) +
              ((double)bf2f((unsigned short)(w6.y >> 16)) + bf2f((unsigned short)(w7.y >> 16)));
    }
    for (; i < e; i++) {
        uint2 wv = p2u[(size_t)csr[i] * 8 + l];
        a0 += (double)bf2f((unsigned short)(wv.x & 0xFFFFu));
        a1 += (double)bf2f((unsigned short)(wv.x >> 16));
        a2 += (double)bf2f((unsigned short)(wv.y & 0xFFFFu));
        a3 += (double)bf2f((unsigned short)(wv.y >> 16));
    }
    double r = (double)dinv[g];
    uint2 o;
    o.x = (unsigned)f2bf((float)(a0 * r)) | ((unsigned)f2bf((float)(a1 * r)) << 16);
    o.y = (unsigned)f2bf((float)(a2 * r)) | ((unsigned)f2bf((float)(a3 * r)) << 16);
    agghu[(size_t)g * 8 + l] = o;  // pads (cols 30,31) are zero-sums -> stay 0
}

// h2 = relu((Ah1)W2[:30] + (Ax)W2[30:] + b2); p3 = ([h2,x]@W3) * dinv.
// Block stages its 256 bf16 aggh rows through LDS (stride-17 uints).
__global__ void k_layer2(const unsigned short* aggh, const float2* aggx,
                         const float* x, const float* W2, const float* W3,
                         const float* b2, const float* dinv, float* p3, int n) {
    __shared__ float W2s[32 * 30];
    __shared__ float W3s[32];
    __shared__ float b2s[30];
    __shared__ unsigned hsh[256 * 17];
    int t = threadIdx.x;
    for (int i = t; i < 960; i += 256) W2s[i] = W2[i];
    if (t < 32) W3s[t] = W3[t];
    if (t < 30) b2s[t] = b2[t];
    const unsigned* ag = (const unsigned*)aggh + (size_t)blockIdx.x * 256 * 16;
    int rows = min(256, n - blockIdx.x * 256);
    for (int i = t; i < rows * 16; i += 256) {
        int rr = i >> 4, cc = i & 15;
        hsh[rr * 17 + cc] = ag[i];
    }
    __syncthreads();
    int v = blockIdx.x * 256 + t;
    if (v >= n) return;
    float2 a = aggx[v];
    float acc[30];
#pragma unroll
    for (int j = 0; j < 30; j++)
        acc[j] = fmaf(a.x, W2s[30 * 30 + j], fmaf(a.y, W2s[31 * 30 + j], b2s[j]));
#pragma unroll
    for (int kk = 0; kk < 15; kk++) {  // 30 values = 15 uint pairs
        unsigned pr = hsh[t * 17 + kk];
        float h0 = bf2f((unsigned short)(pr & 0xFFFFu));
        float h1v = bf2f((unsigned short)(pr >> 16));
#pragma unroll
        for (int j = 0; j < 30; j++)
            acc[j] = fmaf(h0, W2s[(2 * kk) * 30 + j], acc[j]);
#pragma unroll
        for (int j = 0; j < 30; j++)
            acc[j] = fmaf(h1v, W2s[(2 * kk + 1) * 30 + j], acc[j]);
    }
    float s3 = 0.f;
#pragma unroll
    for (int j = 0; j < 30; j++) s3 = fmaf(fmaxf(acc[j], 0.f), W3s[j], s3);
    s3 = fmaf(x[2 * v], W3s[30], s3);
    s3 = fmaf(x[2 * v + 1], W3s[31], s3);
    p3[v] = s3 * dinv[v];
}

// out_v = dinv_v * (p3_v + sum p3_u) + b3   (dim 1, x8 unroll, fp64 acc)
__global__ void k_agg1(const float* p3, const int2* iptr2, const int* csr,
                       const float* dinv, const float* b3, float* out, int n) {
    int v = blockIdx.x * 256 + threadIdx.x;
    if (v >= n) return;
    double acc = (double)p3[v];
    int2 se = iptr2[v];
    int s = se.x, e = se.y;
    int i = s;
    for (; i + 7 < e; i += 8) {
        int u0 = csr[i], u1 = csr[i + 1], u2 = csr[i + 2], u3 = csr[i + 3];
        int u4 = csr[i + 4], u5 = csr[i + 5], u6 = csr[i + 6], u7 = csr[i + 7];
        float f0 = p3[u0], f1 = p3[u1], f2 = p3[u2], f3 = p3[u3];
        float f4 = p3[u4], f5 = p3[u5], f6 = p3[u6], f7 = p3[u7];
        acc += ((double)f0 + f1) + ((double)f2 + f3) +
               ((double)f4 + f5) + ((double)f6 + f7);
    }
    for (; i < e; i++) acc += (double)p3[csr[i]];
    out[v] = (float)(acc * (double)dinv[v] + (double)b3[0]);
}

extern "C" void kernel_launch(void* const* d_in, const int* in_sizes, int n_in,
                              void* d_out, int out_size, void* d_ws, size_t ws_size,
                              hipStream_t stream) {
    const float* x  = (const float*)d_in[0];
    const void*  ei = d_in[1];
    const float* W1 = (const float*)d_in[2];
    const float* b1 = (const float*)d_in[3];
    const float* W2 = (const float*)d_in[4];
    const float* b2 = (const float*)d_in[5];
    const float* W3 = (const float*)d_in[6];
    const float* b3 = (const float*)d_in[7];
    float* out = (float*)d_out;
    const int n = in_sizes[0] / 2;
    const long long E = in_sizes[1] / 2;
    const int B = (n + 511) / 512;  // dst buckets of 512 nodes (<=512 buckets)

    char* w = (char*)d_ws;
    auto alloc = [&](size_t b) { void* p = (void*)w; w += (b + 255) & ~(size_t)255; return p; };
    int*            gcnt   = (int*)alloc(512 * 4);
    unsigned*       binned = (unsigned*)alloc((size_t)B * CAP * 4);
    int*            csr    = (int*)alloc((size_t)B * CAP * 4);
    int2*           iptr2  = (int2*)alloc((size_t)n * 8);
    float*          dinv   = (float*)alloc((size_t)n * 4);
    float2*         p1     = (float2*)alloc((size_t)n * 8);
    float2*         aggx   = (float2*)alloc((size_t)n * 8);
    unsigned short* p2     = (unsigned short*)alloc((size_t)n * 32 * 2);
    unsigned short* aggh   = (unsigned short*)alloc((size_t)n * 32 * 2);
    float*          p3     = (float*)alloc((size_t)n * 4);

    int nblocks = (n + 255) / 256;
    int nbin = (int)((E + CHUNK - 1) / CHUNK);

    hipMemsetAsync(gcnt, 0, 512 * 4, stream);
    k_bin<<<nbin, 512, 0, stream>>>(ei, E, gcnt, binned, B);
    k_bucket_csr<<<B, 1024, 0, stream>>>(binned, gcnt, x, iptr2, dinv, p1, csr, n);
    k_agg2_l1<<<nblocks, 256, 0, stream>>>(p1, iptr2, csr, dinv, W1, b1, aggx, p2, n);
    k_agg30<<<(n + 31) / 32, 256, 0, stream>>>((const uint2*)p2, iptr2, csr, dinv,
                                               (uint2*)aggh, n);
    k_layer2<<<nblocks, 256, 0, stream>>>(aggh, aggx, x, W2, W3, b2, dinv, p3, n);
    k_agg1<<<nblocks, 256, 0, stream>>>(p3, iptr2, csr, dinv, b3, out, n);
}

// Round 3
// 222.345 us; speedup vs baseline: 1.2119x; 1.1269x over previous
//
#include <hip/hip_runtime.h>
#include <stdint.h>

// 3-layer GCN, gather-only aggregation off a per-node CSR.
// R18 = R15 locked base (k_bin pairs, direct-scatter k_bucket_csr) + ONE
// structural change: the dim-30 aggregation no longer gathers precomputed
// 64B bf16 rows. p2[u] was a pure function of (ax_u, ay_u, r_u), so k_agg30
// now gathers a 16B float4 per neighbor from a 3.2MB table (L2-resident per
// XCD) and recomputes the 30 h-dims in-register (4 dims/lane, weights in
// regs). Demand 205MB -> 51MB, FETCH ~157MB -> ~45MB. fp32 h (vs bf16 rows)
// is strictly closer to the reference. k_agg2_l1 drops the p2 pack/store
// entirely; k_layer2 reads t4 (ax,ay,r) instead of aggx+dinv.
//  k_bin: CHUNK 6400, fused hist+LDS-sort+linear copy-out, shuffle scan,
//         edge list consumed in pairs (int2/longlong2 vector loads).
//  k_bucket_csr: 1024 thr, shuffle scan, direct scatter to owned region.
//  k_agg2_l1 / k_agg30 / k_layer2 / k_agg1: unrolled cached gathers,
//  fp64 accumulators (order-independent), bf16 64B rows for aggh.
// Packed edge = (src<<9)|(dst&511), src < 2^18.

#define CAP 9216    // bucket region capacity; mean 8184, sigma 90 -> +11 sigma
#define CHUNK 6400  // edges per k_bin block

__device__ __forceinline__ unsigned short f2bf(float f) {  // RNE, no NaN inputs
    unsigned u = __float_as_uint(f);
    unsigned r = ((u >> 16) & 1u) + 0x7FFFu;
    return (unsigned short)((u + r) >> 16);
}
__device__ __forceinline__ float bf2f(unsigned short h) {
    return __uint_as_float((unsigned)h << 16);
}

// Per-block int64-vs-int32 detect: int64 edge values < 2^18 => all high
// words zero; int32 data at those offsets is src values, ~surely nonzero.
__device__ __forceinline__ int detect64(const unsigned* ei, int* s_nz, int t) {
    unsigned v = ei[2 * (t & 255) + 1];
    if (v != 0) atomicAdd(s_nz, 1);
    __syncthreads();
    return (*s_nz == 0);
}

// Fused binning with local counting sort and coalesced copy-out. 512 thr.
// Edge list consumed in PAIRS via vector loads.
__global__ __launch_bounds__(512) void k_bin(const void* ei, long long E,
                                             int* gcnt, unsigned* binned, int B) {
    __shared__ int cursor[512];
    __shared__ int delta[512];
    __shared__ int wsum[8];
    __shared__ int s_total;
    __shared__ unsigned sv[CHUNK];
    __shared__ unsigned short sb[CHUNK];
    __shared__ int s_nz;
    int t = threadIdx.x, blk = blockIdx.x;
    if (t == 0) s_nz = 0;
    cursor[t] = 0;
    __syncthreads();
    int f = detect64((const unsigned*)ei, &s_nz, t);
    long long s = (long long)blk * CHUNK, e = min(E, s + CHUNK);
    // ---- histogram (pairs) ----
    if (f) {
        const long long* p = (const long long*)ei;
        long long i = s + 2 * t;
        for (; i + 1 < e; i += 1024) {
            longlong2 d = *(const longlong2*)(p + E + i);
            atomicAdd(&cursor[((int)d.x) >> 9], 1);
            atomicAdd(&cursor[((int)d.y) >> 9], 1);
        }
        if (i < e) atomicAdd(&cursor[((int)p[E + i]) >> 9], 1);
    } else {
        const int* p = (const int*)ei;
        long long i = s + 2 * t;
        for (; i + 1 < e; i += 1024) {
            int2 d = *(const int2*)(p + E + i);
            atomicAdd(&cursor[d.x >> 9], 1);
            atomicAdd(&cursor[d.y >> 9], 1);
        }
        if (i < e) atomicAdd(&cursor[p[E + i] >> 9], 1);
    }
    __syncthreads();
    // exclusive scan over 512 counts: wave shuffle scan + cross-wave offsets
    int c = cursor[t];
    int lane = t & 63, wid = t >> 6;
    int inc = c;
#pragma unroll
    for (int off = 1; off < 64; off <<= 1) {
        int up = __shfl_up(inc, off, 64);
        if (lane >= off) inc += up;
    }
    if (lane == 63) wsum[wid] = inc;
    __syncthreads();
    int base = 0;
    for (int k = 0; k < wid; k++) base += wsum[k];
    int ex = base + inc - c;
    if (t == 511) s_total = ex + c;
    int claim = c ? atomicAdd(&gcnt[t], c) : 0;
    delta[t] = t * CAP + claim - ex;
    cursor[t] = ex;
    __syncthreads();
    // ---- scatter into LDS (pairs), remember bucket id ----
    if (f) {
        const long long* p = (const long long*)ei;
        long long i = s + 2 * t;
        for (; i + 1 < e; i += 1024) {
            longlong2 sp = *(const longlong2*)(p + i);
            longlong2 dp = *(const longlong2*)(p + E + i);
            int b0 = ((int)dp.x) >> 9, b1 = ((int)dp.y) >> 9;
            int p0 = atomicAdd(&cursor[b0], 1);
            sv[p0] = ((unsigned)(int)sp.x << 9) | (unsigned)((int)dp.x & 511);
            sb[p0] = (unsigned short)b0;
            int p1v = atomicAdd(&cursor[b1], 1);
            sv[p1v] = ((unsigned)(int)sp.y << 9) | (unsigned)((int)dp.y & 511);
            sb[p1v] = (unsigned short)b1;
        }
        if (i < e) {
            int sval = (int)p[i], dv = (int)p[E + i];
            int b = dv >> 9;
            int pos = atomicAdd(&cursor[b], 1);
            sv[pos] = ((unsigned)sval << 9) | (unsigned)(dv & 511);
            sb[pos] = (unsigned short)b;
        }
    } else {
        const int* p = (const int*)ei;
        long long i = s + 2 * t;
        for (; i + 1 < e; i += 1024) {
            int2 sp = *(const int2*)(p + i);
            int2 dp = *(const int2*)(p + E + i);
            int b0 = dp.x >> 9, b1 = dp.y >> 9;
            int p0 = atomicAdd(&cursor[b0], 1);
            sv[p0] = ((unsigned)sp.x << 9) | (unsigned)(dp.x & 511);
            sb[p0] = (unsigned short)b0;
            int p1v = atomicAdd(&cursor[b1], 1);
            sv[p1v] = ((unsigned)sp.y << 9) | (unsigned)(dp.y & 511);
            sb[p1v] = (unsigned short)b1;
        }
        if (i < e) {
            int sval = p[i], dv = p[E + i];
            int b = dv >> 9;
            int pos = atomicAdd(&cursor[b], 1);
            sv[pos] = ((unsigned)sval << 9) | (unsigned)(dv & 511);
            sb[pos] = (unsigned short)b;
        }
    }
    __syncthreads();
    // linear copy-out (consecutive threads -> consecutive addresses)
    int total = s_total;
    for (int i = t; i < total; i += 512)
        binned[delta[sb[i]] + i] = sv[i];
}

// Per-bucket counting sort by local node, scattering csr DIRECTLY to the
// block-owned global region. 1024 threads; shuffle scan over 512 counters.
// Also iptr2, dinv, p1 = x*dinv.
__global__ __launch_bounds__(1024) void k_bucket_csr(
        const unsigned* binned, const int* gcnt, const float* x, int2* iptr2,
        float* dinv, float2* p1, int* csr, int n) {
    __shared__ int cur[512];
    __shared__ int wsum[16];
    int t = threadIdx.x, b = blockIdx.x;
    if (t < 512) cur[t] = 0;
    __syncthreads();
    int cnt = gcnt[b];
    const unsigned* bp = binned + (size_t)b * CAP;
    for (int i = t; i < cnt; i += 1024)
        atomicAdd(&cur[bp[i] & 511u], 1);
    __syncthreads();
    int c = (t < 512) ? cur[t] : 0;
    int lane = t & 63, wid = t >> 6;
    int inc = c;
#pragma unroll
    for (int off = 1; off < 64; off <<= 1) {
        int up = __shfl_up(inc, off, 64);
        if (lane >= off) inc += up;
    }
    if (lane == 63) wsum[wid] = inc;
    __syncthreads();
    int base = 0;
    for (int k = 0; k < wid; k++) base += wsum[k];
    int ex = base + inc - c;
    int gbase = b * CAP;
    if (t < 512) {
        cur[t] = gbase + ex;  // global cursor
        int node = b * 512 + t;
        if (node < n) {
            iptr2[node] = make_int2(gbase + ex, gbase + ex + c);
            float dg = (float)(c + 1);  // +1 self loop
            float r = rsqrtf(dg);
            r = r * (1.5f - 0.5f * dg * r * r);  // Newton refine
            dinv[node] = r;
            p1[node] = make_float2(x[2 * node] * r, x[2 * node + 1] * r);
        }
    }
    __syncthreads();
    for (int i = t; i < cnt; i += 1024) {
        unsigned p = bp[i];
        int pos = atomicAdd(&cur[p & 511u], 1);
        csr[pos] = (int)(p >> 9);
    }
}

// Fused: aggx = A_hat x (dim2, x8 unroll, fp64 acc);
// t4 = (ax, ay, dinv, 0) -- the 16B generator of this node's h-row.
__global__ void k_agg2_l1(const float2* p1, const int2* iptr2, const int* csr,
                          const float* dinv, float4* t4, int n) {
    int v = blockIdx.x * 256 + threadIdx.x;
    if (v >= n) return;
    float2 a0 = p1[v];
    double dax = a0.x, day = a0.y;
    int2 se = iptr2[v];
    int s = se.x, e = se.y;
    int i = s;
    for (; i + 7 < e; i += 8) {
        int u0 = csr[i], u1 = csr[i + 1], u2 = csr[i + 2], u3 = csr[i + 3];
        int u4 = csr[i + 4], u5 = csr[i + 5], u6 = csr[i + 6], u7 = csr[i + 7];
        float2 q0 = p1[u0], q1 = p1[u1], q2 = p1[u2], q3 = p1[u3];
        float2 q4 = p1[u4], q5 = p1[u5], q6 = p1[u6], q7 = p1[u7];
        dax += ((double)q0.x + q1.x) + ((double)q2.x + q3.x) +
               ((double)q4.x + q5.x) + ((double)q6.x + q7.x);
        day += ((double)q0.y + q1.y) + ((double)q2.y + q3.y) +
               ((double)q4.y + q5.y) + ((double)q6.y + q7.y);
    }
    for (; i < e; i++) {
        float2 q = p1[csr[i]];
        dax += (double)q.x; day += (double)q.y;
    }
    float r = dinv[v];
    float ax = (float)(dax * (double)r), ay = (float)(day * (double)r);
    t4[v] = make_float4(ax, ay, r, 0.f);
}

// Dim-30 aggregation by RECOMPUTE: 8-lane group per node; each lane owns
// dims 4l..4l+3 (W1 columns in registers). Per neighbor: one broadcast 16B
// float4 gather from the 3.2MB t4 table (L2-resident), then
// h_j = relu(ax*W1[j] + ay*W1[30+j] + b1[j]) * r  recomputed in fp32,
// accumulated in fp64. Output aggh bf16 rows, identical layout to before.
__global__ void k_agg30(const float4* t4, const int2* iptr2, const int* csr,
                        const float* W1, const float* b1,
                        uint2* agghu, int n) {
    int t = threadIdx.x;
    int g = blockIdx.x * 32 + (t >> 3);
    int l = t & 7;
    if (g >= n) return;
    float w0[4], w1[4], bb[4];
#pragma unroll
    for (int k = 0; k < 4; k++) {
        int j = 4 * l + k;
        bool ok = (j < 30);
        w0[k] = ok ? W1[j] : 0.f;
        w1[k] = ok ? W1[30 + j] : 0.f;
        bb[k] = ok ? b1[j] : 0.f;
    }
    float4 qs = t4[g];  // self
    double a0, a1, a2, a3;
    {
        float h0 = fmaxf(fmaf(qs.x, w0[0], fmaf(qs.y, w1[0], bb[0])), 0.f) * qs.z;
        float h1 = fmaxf(fmaf(qs.x, w0[1], fmaf(qs.y, w1[1], bb[1])), 0.f) * qs.z;
        float h2 = fmaxf(fmaf(qs.x, w0[2], fmaf(qs.y, w1[2], bb[2])), 0.f) * qs.z;
        float h3 = fmaxf(fmaf(qs.x, w0[3], fmaf(qs.y, w1[3], bb[3])), 0.f) * qs.z;
        a0 = h0; a1 = h1; a2 = h2; a3 = h3;
    }
#define DIM4(q)                                                                  \
    {                                                                            \
        float h0 = fmaxf(fmaf(q.x, w0[0], fmaf(q.y, w1[0], bb[0])), 0.f) * q.z;  \
        float h1 = fmaxf(fmaf(q.x, w0[1], fmaf(q.y, w1[1], bb[1])), 0.f) * q.z;  \
        float h2 = fmaxf(fmaf(q.x, w0[2], fmaf(q.y, w1[2], bb[2])), 0.f) * q.z;  \
        float h3 = fmaxf(fmaf(q.x, w0[3], fmaf(q.y, w1[3], bb[3])), 0.f) * q.z;  \
        a0 += (double)h0; a1 += (double)h1; a2 += (double)h2; a3 += (double)h3;  \
    }
    int2 se = iptr2[g];
    int s = se.x, e = se.y;
    int i = s;
    for (; i + 3 < e; i += 4) {
        int u0 = csr[i], u1 = csr[i + 1], u2 = csr[i + 2], u3 = csr[i + 3];
        float4 q0 = t4[u0], q1 = t4[u1], q2 = t4[u2], q3 = t4[u3];
        DIM4(q0); DIM4(q1); DIM4(q2); DIM4(q3);
    }
    for (; i < e; i++) {
        float4 q = t4[csr[i]];
        DIM4(q);
    }
#undef DIM4
    double r = (double)qs.z;
    uint2 o;
    o.x = (unsigned)f2bf((float)(a0 * r)) | ((unsigned)f2bf((float)(a1 * r)) << 16);
    o.y = (unsigned)f2bf((float)(a2 * r)) | ((unsigned)f2bf((float)(a3 * r)) << 16);
    agghu[(size_t)g * 8 + l] = o;  // pads (cols 30,31) are zero -> stay 0
}

// h2 = relu((Ah1)W2[:30] + (Ax)W2[30:] + b2); p3 = ([h2,x]@W3) * dinv.
// Block stages its 256 bf16 aggh rows through LDS (stride-17 uints).
// Reads t4 for (ax, ay, dinv).
__global__ void k_layer2(const unsigned short* aggh, const float4* t4,
                         const float* x, const float* W2, const float* W3,
                         const float* b2, float* p3, int n) {
    __shared__ float W2s[32 * 30];
    __shared__ float W3s[32];
    __shared__ float b2s[30];
    __shared__ unsigned hsh[256 * 17];
    int t = threadIdx.x;
    for (int i = t; i < 960; i += 256) W2s[i] = W2[i];
    if (t < 32) W3s[t] = W3[t];
    if (t < 30) b2s[t] = b2[t];
    const unsigned* ag = (const unsigned*)aggh + (size_t)blockIdx.x * 256 * 16;
    int rows = min(256, n - blockIdx.x * 256);
    for (int i = t; i < rows * 16; i += 256) {
        int rr = i >> 4, cc = i & 15;
        hsh[rr * 17 + cc] = ag[i];
    }
    __syncthreads();
    int v = blockIdx.x * 256 + t;
    if (v >= n) return;
    float4 a = t4[v];
    float acc[30];
#pragma unroll
    for (int j = 0; j < 30; j++)
        acc[j] = fmaf(a.x, W2s[30 * 30 + j], fmaf(a.y, W2s[31 * 30 + j], b2s[j]));
#pragma unroll
    for (int kk = 0; kk < 15; kk++) {  // 30 values = 15 uint pairs
        unsigned pr = hsh[t * 17 + kk];
        float h0 = bf2f((unsigned short)(pr & 0xFFFFu));
        float h1v = bf2f((unsigned short)(pr >> 16));
#pragma unroll
        for (int j = 0; j < 30; j++)
            acc[j] = fmaf(h0, W2s[(2 * kk) * 30 + j], acc[j]);
#pragma unroll
        for (int j = 0; j < 30; j++)
            acc[j] = fmaf(h1v, W2s[(2 * kk + 1) * 30 + j], acc[j]);
    }
    float s3 = 0.f;
#pragma unroll
    for (int j = 0; j < 30; j++) s3 = fmaf(fmaxf(acc[j], 0.f), W3s[j], s3);
    s3 = fmaf(x[2 * v], W3s[30], s3);
    s3 = fmaf(x[2 * v + 1], W3s[31], s3);
    p3[v] = s3 * a.z;
}

// out_v = dinv_v * (p3_v + sum p3_u) + b3   (dim 1, x8 unroll, fp64 acc)
__global__ void k_agg1(const float* p3, const int2* iptr2, const int* csr,
                       const float* dinv, const float* b3, float* out, int n) {
    int v = blockIdx.x * 256 + threadIdx.x;
    if (v >= n) return;
    double acc = (double)p3[v];
    int2 se = iptr2[v];
    int s = se.x, e = se.y;
    int i = s;
    for (; i + 7 < e; i += 8) {
        int u0 = csr[i], u1 = csr[i + 1], u2 = csr[i + 2], u3 = csr[i + 3];
        int u4 = csr[i + 4], u5 = csr[i + 5], u6 = csr[i + 6], u7 = csr[i + 7];
        float f0 = p3[u0], f1 = p3[u1], f2 = p3[u2], f3 = p3[u3];
        float f4 = p3[u4], f5 = p3[u5], f6 = p3[u6], f7 = p3[u7];
        acc += ((double)f0 + f1) + ((double)f2 + f3) +
               ((double)f4 + f5) + ((double)f6 + f7);
    }
    for (; i < e; i++) acc += (double)p3[csr[i]];
    out[v] = (float)(acc * (double)dinv[v] + (double)b3[0]);
}

extern "C" void kernel_launch(void* const* d_in, const int* in_sizes, int n_in,
                              void* d_out, int out_size, void* d_ws, size_t ws_size,
                              hipStream_t stream) {
    const float* x  = (const float*)d_in[0];
    const void*  ei = d_in[1];
    const float* W1 = (const float*)d_in[2];
    const float* b1 = (const float*)d_in[3];
    const float* W2 = (const float*)d_in[4];
    const float* b2 = (const float*)d_in[5];
    const float* W3 = (const float*)d_in[6];
    const float* b3 = (const float*)d_in[7];
    float* out = (float*)d_out;
    const int n = in_sizes[0] / 2;
    const long long E = in_sizes[1] / 2;
    const int B = (n + 511) / 512;  // dst buckets of 512 nodes (<=512 buckets)

    char* w = (char*)d_ws;
    auto alloc = [&](size_t b) { void* p = (void*)w; w += (b + 255) & ~(size_t)255; return p; };
    int*            gcnt   = (int*)alloc(512 * 4);
    unsigned*       binned = (unsigned*)alloc((size_t)B * CAP * 4);
    int*            csr    = (int*)alloc((size_t)B * CAP * 4);
    int2*           iptr2  = (int2*)alloc((size_t)n * 8);
    float*          dinv   = (float*)alloc((size_t)n * 4);
    float2*         p1     = (float2*)alloc((size_t)n * 8);
    float4*         t4     = (float4*)alloc((size_t)n * 16);
    unsigned short* aggh   = (unsigned short*)alloc((size_t)n * 32 * 2);
    float*          p3     = (float*)alloc((size_t)n * 4);

    int nblocks = (n + 255) / 256;
    int nbin = (int)((E + CHUNK - 1) / CHUNK);

    hipMemsetAsync(gcnt, 0, 512 * 4, stream);
    k_bin<<<nbin, 512, 0, stream>>>(ei, E, gcnt, binned, B);
    k_bucket_csr<<<B, 1024, 0, stream>>>(binned, gcnt, x, iptr2, dinv, p1, csr, n);
    k_agg2_l1<<<nblocks, 256, 0, stream>>>(p1, iptr2, csr, dinv, t4, n);
    k_agg30<<<(n + 31) / 32, 256, 0, stream>>>(t4, iptr2, csr, W1, b1,
                                               (uint2*)aggh, n);
    k_layer2<<<nblocks, 256, 0, stream>>>(aggh, t4, x, W2, W3, b2, p3, n);
    k_agg1<<<nblocks, 256, 0, stream>>>(p3, iptr2, csr, dinv, b3, out, n);
}

// Round 4
// 221.982 us; speedup vs baseline: 1.2139x; 1.0016x over previous
//
#include <hip/hip_runtime.h>
#include <stdint.h>

// 3-layer GCN, gather-only aggregation off a per-node CSR.
// R19 = R18 + fp32 accumulators in the three gather kernels (was fp64):
// k_agg30's per-dim chain goes {fma,fma,max,mul,cvt,f64add} -> {fma,fma,max,
// fma} (scale folded into the accumulate fma) = -33% VALU instructions on a
// 67%-VALUBusy kernel; gather unroll deepened 4->8 (mean deg ~16). k_agg2_l1
// and k_agg1 use fp32 pairwise trees. Numerics: fp32 sum of ~16 O(1) values
// adds ~1e-6 abs error vs the 2^-10 absmax already set by bf16 aggh rounding.
//  k_bin: CHUNK 6400, fused hist+LDS-sort+linear copy-out, shuffle scan,
//         edge list consumed in pairs (int2/longlong2 vector loads).
//  k_bucket_csr: 1024 thr, shuffle scan, direct scatter to owned region.
//  k_agg30: RECOMPUTE form -- gathers 16B float4 (ax,ay,r) from the 3.2MB
//  L2-resident t4 table and rebuilds the 30 h-dims in-register (4 dims/lane,
//  8 lanes/node); FETCH 26MB (was 157MB with the 64B bf16-row gather).
// Packed edge = (src<<9)|(dst&511), src < 2^18.

#define CAP 9216    // bucket region capacity; mean 8184, sigma 90 -> +11 sigma
#define CHUNK 6400  // edges per k_bin block

__device__ __forceinline__ unsigned short f2bf(float f) {  // RNE, no NaN inputs
    unsigned u = __float_as_uint(f);
    unsigned r = ((u >> 16) & 1u) + 0x7FFFu;
    return (unsigned short)((u + r) >> 16);
}
__device__ __forceinline__ float bf2f(unsigned short h) {
    return __uint_as_float((unsigned)h << 16);
}

// Per-block int64-vs-int32 detect: int64 edge values < 2^18 => all high
// words zero; int32 data at those offsets is src values, ~surely nonzero.
__device__ __forceinline__ int detect64(const unsigned* ei, int* s_nz, int t) {
    unsigned v = ei[2 * (t & 255) + 1];
    if (v != 0) atomicAdd(s_nz, 1);
    __syncthreads();
    return (*s_nz == 0);
}

// Fused binning with local counting sort and coalesced copy-out. 512 thr.
// Edge list consumed in PAIRS via vector loads.
__global__ __launch_bounds__(512) void k_bin(const void* ei, long long E,
                                             int* gcnt, unsigned* binned, int B) {
    __shared__ int cursor[512];
    __shared__ int delta[512];
    __shared__ int wsum[8];
    __shared__ int s_total;
    __shared__ unsigned sv[CHUNK];
    __shared__ unsigned short sb[CHUNK];
    __shared__ int s_nz;
    int t = threadIdx.x, blk = blockIdx.x;
    if (t == 0) s_nz = 0;
    cursor[t] = 0;
    __syncthreads();
    int f = detect64((const unsigned*)ei, &s_nz, t);
    long long s = (long long)blk * CHUNK, e = min(E, s + CHUNK);
    // ---- histogram (pairs) ----
    if (f) {
        const long long* p = (const long long*)ei;
        long long i = s + 2 * t;
        for (; i + 1 < e; i += 1024) {
            longlong2 d = *(const longlong2*)(p + E + i);
            atomicAdd(&cursor[((int)d.x) >> 9], 1);
            atomicAdd(&cursor[((int)d.y) >> 9], 1);
        }
        if (i < e) atomicAdd(&cursor[((int)p[E + i]) >> 9], 1);
    } else {
        const int* p = (const int*)ei;
        long long i = s + 2 * t;
        for (; i + 1 < e; i += 1024) {
            int2 d = *(const int2*)(p + E + i);
            atomicAdd(&cursor[d.x >> 9], 1);
            atomicAdd(&cursor[d.y >> 9], 1);
        }
        if (i < e) atomicAdd(&cursor[p[E + i] >> 9], 1);
    }
    __syncthreads();
    // exclusive scan over 512 counts: wave shuffle scan + cross-wave offsets
    int c = cursor[t];
    int lane = t & 63, wid = t >> 6;
    int inc = c;
#pragma unroll
    for (int off = 1; off < 64; off <<= 1) {
        int up = __shfl_up(inc, off, 64);
        if (lane >= off) inc += up;
    }
    if (lane == 63) wsum[wid] = inc;
    __syncthreads();
    int base = 0;
    for (int k = 0; k < wid; k++) base += wsum[k];
    int ex = base + inc - c;
    if (t == 511) s_total = ex + c;
    int claim = c ? atomicAdd(&gcnt[t], c) : 0;
    delta[t] = t * CAP + claim - ex;
    cursor[t] = ex;
    __syncthreads();
    // ---- scatter into LDS (pairs), remember bucket id ----
    if (f) {
        const long long* p = (const long long*)ei;
        long long i = s + 2 * t;
        for (; i + 1 < e; i += 1024) {
            longlong2 sp = *(const longlong2*)(p + i);
            longlong2 dp = *(const longlong2*)(p + E + i);
            int b0 = ((int)dp.x) >> 9, b1 = ((int)dp.y) >> 9;
            int p0 = atomicAdd(&cursor[b0], 1);
            sv[p0] = ((unsigned)(int)sp.x << 9) | (unsigned)((int)dp.x & 511);
            sb[p0] = (unsigned short)b0;
            int p1v = atomicAdd(&cursor[b1], 1);
            sv[p1v] = ((unsigned)(int)sp.y << 9) | (unsigned)((int)dp.y & 511);
            sb[p1v] = (unsigned short)b1;
        }
        if (i < e) {
            int sval = (int)p[i], dv = (int)p[E + i];
            int b = dv >> 9;
            int pos = atomicAdd(&cursor[b], 1);
            sv[pos] = ((unsigned)sval << 9) | (unsigned)(dv & 511);
            sb[pos] = (unsigned short)b;
        }
    } else {
        const int* p = (const int*)ei;
        long long i = s + 2 * t;
        for (; i + 1 < e; i += 1024) {
            int2 sp = *(const int2*)(p + i);
            int2 dp = *(const int2*)(p + E + i);
            int b0 = dp.x >> 9, b1 = dp.y >> 9;
            int p0 = atomicAdd(&cursor[b0], 1);
            sv[p0] = ((unsigned)sp.x << 9) | (unsigned)(dp.x & 511);
            sb[p0] = (unsigned short)b0;
            int p1v = atomicAdd(&cursor[b1], 1);
            sv[p1v] = ((unsigned)sp.y << 9) | (unsigned)(dp.y & 511);
            sb[p1v] = (unsigned short)b1;
        }
        if (i < e) {
            int sval = p[i], dv = p[E + i];
            int b = dv >> 9;
            int pos = atomicAdd(&cursor[b], 1);
            sv[pos] = ((unsigned)sval << 9) | (unsigned)(dv & 511);
            sb[pos] = (unsigned short)b;
        }
    }
    __syncthreads();
    // linear copy-out (consecutive threads -> consecutive addresses)
    int total = s_total;
    for (int i = t; i < total; i += 512)
        binned[delta[sb[i]] + i] = sv[i];
}

// Per-bucket counting sort by local node, scattering csr DIRECTLY to the
// block-owned global region. 1024 threads; shuffle scan over 512 counters.
// Also iptr2, dinv, p1 = x*dinv.
__global__ __launch_bounds__(1024) void k_bucket_csr(
        const unsigned* binned, const int* gcnt, const float* x, int2* iptr2,
        float* dinv, float2* p1, int* csr, int n) {
    __shared__ int cur[512];
    __shared__ int wsum[16];
    int t = threadIdx.x, b = blockIdx.x;
    if (t < 512) cur[t] = 0;
    __syncthreads();
    int cnt = gcnt[b];
    const unsigned* bp = binned + (size_t)b * CAP;
    for (int i = t; i < cnt; i += 1024)
        atomicAdd(&cur[bp[i] & 511u], 1);
    __syncthreads();
    int c = (t < 512) ? cur[t] : 0;
    int lane = t & 63, wid = t >> 6;
    int inc = c;
#pragma unroll
    for (int off = 1; off < 64; off <<= 1) {
        int up = __shfl_up(inc, off, 64);
        if (lane >= off) inc += up;
    }
    if (lane == 63) wsum[wid] = inc;
    __syncthreads();
    int base = 0;
    for (int k = 0; k < wid; k++) base += wsum[k];
    int ex = base + inc - c;
    int gbase = b * CAP;
    if (t < 512) {
        cur[t] = gbase + ex;  // global cursor
        int node = b * 512 + t;
        if (node < n) {
            iptr2[node] = make_int2(gbase + ex, gbase + ex + c);
            float dg = (float)(c + 1);  // +1 self loop
            float r = rsqrtf(dg);
            r = r * (1.5f - 0.5f * dg * r * r);  // Newton refine
            dinv[node] = r;
            p1[node] = make_float2(x[2 * node] * r, x[2 * node + 1] * r);
        }
    }
    __syncthreads();
    for (int i = t; i < cnt; i += 1024) {
        unsigned p = bp[i];
        int pos = atomicAdd(&cur[p & 511u], 1);
        csr[pos] = (int)(p >> 9);
    }
}

// Fused: aggx = A_hat x (dim2, x8 unroll, fp32 pairwise-tree acc);
// t4 = (ax, ay, dinv, 0) -- the 16B generator of this node's h-row.
__global__ void k_agg2_l1(const float2* p1, const int2* iptr2, const int* csr,
                          const float* dinv, float4* t4, int n) {
    int v = blockIdx.x * 256 + threadIdx.x;
    if (v >= n) return;
    float2 a0 = p1[v];
    float dax = a0.x, day = a0.y;
    int2 se = iptr2[v];
    int s = se.x, e = se.y;
    int i = s;
    for (; i + 7 < e; i += 8) {
        int u0 = csr[i], u1 = csr[i + 1], u2 = csr[i + 2], u3 = csr[i + 3];
        int u4 = csr[i + 4], u5 = csr[i + 5], u6 = csr[i + 6], u7 = csr[i + 7];
        float2 q0 = p1[u0], q1 = p1[u1], q2 = p1[u2], q3 = p1[u3];
        float2 q4 = p1[u4], q5 = p1[u5], q6 = p1[u6], q7 = p1[u7];
        dax += ((q0.x + q1.x) + (q2.x + q3.x)) + ((q4.x + q5.x) + (q6.x + q7.x));
        day += ((q0.y + q1.y) + (q2.y + q3.y)) + ((q4.y + q5.y) + (q6.y + q7.y));
    }
    for (; i < e; i++) {
        float2 q = p1[csr[i]];
        dax += q.x; day += q.y;
    }
    float r = dinv[v];
    float ax = dax * r, ay = day * r;
    t4[v] = make_float4(ax, ay, r, 0.f);
}

// Dim-30 aggregation by RECOMPUTE: 8-lane group per node; each lane owns
// dims 4l..4l+3 (W1 columns in registers). Per neighbor: one broadcast 16B
// float4 gather from the 3.2MB t4 table (L2-resident), then
// h_j = relu(ax*W1[j] + ay*W1[30+j] + b1[j]) recomputed in fp32 and
// accumulated scaled via a single fma: acc_j += h_j * r_u. 4 instr/dim.
__global__ void k_agg30(const float4* t4, const int2* iptr2, const int* csr,
                        const float* W1, const float* b1,
                        uint2* agghu, int n) {
    int t = threadIdx.x;
    int g = blockIdx.x * 32 + (t >> 3);
    int l = t & 7;
    if (g >= n) return;
    float w0[4], w1[4], bb[4];
#pragma unroll
    for (int k = 0; k < 4; k++) {
        int j = 4 * l + k;
        bool ok = (j < 30);
        w0[k] = ok ? W1[j] : 0.f;
        w1[k] = ok ? W1[30 + j] : 0.f;
        bb[k] = ok ? b1[j] : 0.f;
    }
    float4 qs = t4[g];  // self
    float a0 = fmaxf(fmaf(qs.x, w0[0], fmaf(qs.y, w1[0], bb[0])), 0.f) * qs.z;
    float a1 = fmaxf(fmaf(qs.x, w0[1], fmaf(qs.y, w1[1], bb[1])), 0.f) * qs.z;
    float a2 = fmaxf(fmaf(qs.x, w0[2], fmaf(qs.y, w1[2], bb[2])), 0.f) * qs.z;
    float a3 = fmaxf(fmaf(qs.x, w0[3], fmaf(qs.y, w1[3], bb[3])), 0.f) * qs.z;
#define DIM4(q)                                                                    \
    {                                                                              \
        a0 = fmaf(fmaxf(fmaf(q.x, w0[0], fmaf(q.y, w1[0], bb[0])), 0.f), q.z, a0); \
        a1 = fmaf(fmaxf(fmaf(q.x, w0[1], fmaf(q.y, w1[1], bb[1])), 0.f), q.z, a1); \
        a2 = fmaf(fmaxf(fmaf(q.x, w0[2], fmaf(q.y, w1[2], bb[2])), 0.f), q.z, a2); \
        a3 = fmaf(fmaxf(fmaf(q.x, w0[3], fmaf(q.y, w1[3], bb[3])), 0.f), q.z, a3); \
    }
    int2 se = iptr2[g];
    int s = se.x, e = se.y;
    int i = s;
    for (; i + 7 < e; i += 8) {
        int u0 = csr[i], u1 = csr[i + 1], u2 = csr[i + 2], u3 = csr[i + 3];
        int u4 = csr[i + 4], u5 = csr[i + 5], u6 = csr[i + 6], u7 = csr[i + 7];
        float4 q0 = t4[u0], q1 = t4[u1], q2 = t4[u2], q3 = t4[u3];
        float4 q4 = t4[u4], q5 = t4[u5], q6 = t4[u6], q7 = t4[u7];
        DIM4(q0); DIM4(q1); DIM4(q2); DIM4(q3);
        DIM4(q4); DIM4(q5); DIM4(q6); DIM4(q7);
    }
    for (; i + 3 < e; i += 4) {
        int u0 = csr[i], u1 = csr[i + 1], u2 = csr[i + 2], u3 = csr[i + 3];
        float4 q0 = t4[u0], q1 = t4[u1], q2 = t4[u2], q3 = t4[u3];
        DIM4(q0); DIM4(q1); DIM4(q2); DIM4(q3);
    }
    for (; i < e; i++) {
        float4 q = t4[csr[i]];
        DIM4(q);
    }
#undef DIM4
    float r = qs.z;
    uint2 o;
    o.x = (unsigned)f2bf(a0 * r) | ((unsigned)f2bf(a1 * r) << 16);
    o.y = (unsigned)f2bf(a2 * r) | ((unsigned)f2bf(a3 * r) << 16);
    agghu[(size_t)g * 8 + l] = o;  // pads (cols 30,31) are zero -> stay 0
}

// h2 = relu((Ah1)W2[:30] + (Ax)W2[30:] + b2); p3 = ([h2,x]@W3) * dinv.
// Block stages its 256 bf16 aggh rows through LDS (stride-17 uints).
// Reads t4 for (ax, ay, dinv).
__global__ void k_layer2(const unsigned short* aggh, const float4* t4,
                         const float* x, const float* W2, const float* W3,
                         const float* b2, float* p3, int n) {
    __shared__ float W2s[32 * 30];
    __shared__ float W3s[32];
    __shared__ float b2s[30];
    __shared__ unsigned hsh[256 * 17];
    int t = threadIdx.x;
    for (int i = t; i < 960; i += 256) W2s[i] = W2[i];
    if (t < 32) W3s[t] = W3[t];
    if (t < 30) b2s[t] = b2[t];
    const unsigned* ag = (const unsigned*)aggh + (size_t)blockIdx.x * 256 * 16;
    int rows = min(256, n - blockIdx.x * 256);
    for (int i = t; i < rows * 16; i += 256) {
        int rr = i >> 4, cc = i & 15;
        hsh[rr * 17 + cc] = ag[i];
    }
    __syncthreads();
    int v = blockIdx.x * 256 + t;
    if (v >= n) return;
    float4 a = t4[v];
    float acc[30];
#pragma unroll
    for (int j = 0; j < 30; j++)
        acc[j] = fmaf(a.x, W2s[30 * 30 + j], fmaf(a.y, W2s[31 * 30 + j], b2s[j]));
#pragma unroll
    for (int kk = 0; kk < 15; kk++) {  // 30 values = 15 uint pairs
        unsigned pr = hsh[t * 17 + kk];
        float h0 = bf2f((unsigned short)(pr & 0xFFFFu));
        float h1v = bf2f((unsigned short)(pr >> 16));
#pragma unroll
        for (int j = 0; j < 30; j++)
            acc[j] = fmaf(h0, W2s[(2 * kk) * 30 + j], acc[j]);
#pragma unroll
        for (int j = 0; j < 30; j++)
            acc[j] = fmaf(h1v, W2s[(2 * kk + 1) * 30 + j], acc[j]);
    }
    float s3 = 0.f;
#pragma unroll
    for (int j = 0; j < 30; j++) s3 = fmaf(fmaxf(acc[j], 0.f), W3s[j], s3);
    s3 = fmaf(x[2 * v], W3s[30], s3);
    s3 = fmaf(x[2 * v + 1], W3s[31], s3);
    p3[v] = s3 * a.z;
}

// out_v = dinv_v * (p3_v + sum p3_u) + b3   (dim 1, x8 unroll, fp32 tree acc)
__global__ void k_agg1(const float* p3, const int2* iptr2, const int* csr,
                       const float* dinv, const float* b3, float* out, int n) {
    int v = blockIdx.x * 256 + threadIdx.x;
    if (v >= n) return;
    float acc = p3[v];
    int2 se = iptr2[v];
    int s = se.x, e = se.y;
    int i = s;
    for (; i + 7 < e; i += 8) {
        int u0 = csr[i], u1 = csr[i + 1], u2 = csr[i + 2], u3 = csr[i + 3];
        int u4 = csr[i + 4], u5 = csr[i + 5], u6 = csr[i + 6], u7 = csr[i + 7];
        float f0 = p3[u0], f1 = p3[u1], f2 = p3[u2], f3 = p3[u3];
        float f4 = p3[u4], f5 = p3[u5], f6 = p3[u6], f7 = p3[u7];
        acc += ((f0 + f1) + (f2 + f3)) + ((f4 + f5) + (f6 + f7));
    }
    for (; i < e; i++) acc += p3[csr[i]];
    out[v] = fmaf(acc, dinv[v], b3[0]);
}

extern "C" void kernel_launch(void* const* d_in, const int* in_sizes, int n_in,
                              void* d_out, int out_size, void* d_ws, size_t ws_size,
                              hipStream_t stream) {
    const float* x  = (const float*)d_in[0];
    const void*  ei = d_in[1];
    const float* W1 = (const float*)d_in[2];
    const float* b1 = (const float*)d_in[3];
    const float* W2 = (const float*)d_in[4];
    const float* b2 = (const float*)d_in[5];
    const float* W3 = (const float*)d_in[6];
    const float* b3 = (const float*)d_in[7];
    float* out = (float*)d_out;
    const int n = in_sizes[0] / 2;
    const long long E = in_sizes[1] / 2;
    const int B = (n + 511) / 512;  // dst buckets of 512 nodes (<=512 buckets)

    char* w = (char*)d_ws;
    auto alloc = [&](size_t b) { void* p = (void*)w; w += (b + 255) & ~(size_t)255; return p; };
    int*            gcnt   = (int*)alloc(512 * 4);
    unsigned*       binned = (unsigned*)alloc((size_t)B * CAP * 4);
    int*            csr    = (int*)alloc((size_t)B * CAP * 4);
    int2*           iptr2  = (int2*)alloc((size_t)n * 8);
    float*          dinv   = (float*)alloc((size_t)n * 4);
    float2*         p1     = (float2*)alloc((size_t)n * 8);
    float4*         t4     = (float4*)alloc((size_t)n * 16);
    unsigned short* aggh   = (unsigned short*)alloc((size_t)n * 32 * 2);
    float*          p3     = (float*)alloc((size_t)n * 4);

    int nblocks = (n + 255) / 256;
    int nbin = (int)((E + CHUNK - 1) / CHUNK);

    hipMemsetAsync(gcnt, 0, 512 * 4, stream);
    k_bin<<<nbin, 512, 0, stream>>>(ei, E, gcnt, binned, B);
    k_bucket_csr<<<B, 1024, 0, stream>>>(binned, gcnt, x, iptr2, dinv, p1, csr, n);
    k_agg2_l1<<<nblocks, 256, 0, stream>>>(p1, iptr2, csr, dinv, t4, n);
    k_agg30<<<(n + 31) / 32, 256, 0, stream>>>(t4, iptr2, csr, W1, b1,
                                               (uint2*)aggh, n);
    k_layer2<<<nblocks, 256, 0, stream>>>(aggh, t4, x, W2, W3, b2, p3, n);
    k_agg1<<<nblocks, 256, 0, stream>>>(p3, iptr2, csr, dinv, b3, out, n);
}

// Round 5
// 219.830 us; speedup vs baseline: 1.2258x; 1.0098x over previous
//
#include <hip/hip_runtime.h>
#include <stdint.h>

// 3-layer GCN, gather-only aggregation off a per-node CSR.
// R20 = R19 with two isolated reversions/fixes:
//  (1) k_bin now reads the edge list ONCE: each thread packs its <=14 chunk
//      edges into statically-indexed register slots during the histogram
//      pass and scatters from registers (was: re-read 51.2MB src+dst from
//      global in the scatter pass). -25.6MB HBM reads + one full VMEM/unpack
//      pass removed.
//  (2) k_agg30's gather loop reverted to the proven 4-unroll (R18 form);
//      R19's 8-unroll raised live-register count (q0..q7 = 32 VGPR) and may
//      have serialized the load burst, masking the fp32 gain. fp32 DIM4 kept.
//  k_bucket_csr: 1024 thr, shuffle scan, direct scatter to owned region.
//  k_agg30: RECOMPUTE form -- gathers 16B float4 (ax,ay,r) from the 3.2MB
//  L2-resident t4 table and rebuilds the 30 h-dims in-register (4 dims/lane,
//  8 lanes/node); FETCH 26MB (was 157MB with the 64B bf16-row gather).
// Packed edge = (src<<9)|(dst&511), src < 2^18.

#define CAP 9216    // bucket region capacity; mean 8184, sigma 90 -> +11 sigma
#define CHUNK 6400  // edges per k_bin block

__device__ __forceinline__ unsigned short f2bf(float f) {  // RNE, no NaN inputs
    unsigned u = __float_as_uint(f);
    unsigned r = ((u >> 16) & 1u) + 0x7FFFu;
    return (unsigned short)((u + r) >> 16);
}
__device__ __forceinline__ float bf2f(unsigned short h) {
    return __uint_as_float((unsigned)h << 16);
}

// Per-block int64-vs-int32 detect: int64 edge values < 2^18 => all high
// words zero; int32 data at those offsets is src values, ~surely nonzero.
__device__ __forceinline__ int detect64(const unsigned* ei, int* s_nz, int t) {
    unsigned v = ei[2 * (t & 255) + 1];
    if (v != 0) atomicAdd(s_nz, 1);
    __syncthreads();
    return (*s_nz == 0);
}

// Fused binning with local counting sort and coalesced copy-out. 512 thr.
// Edge list read ONCE (pairs via vector loads); packed edges + bucket ids
// held in statically-indexed registers across the scan.
__global__ __launch_bounds__(512) void k_bin(const void* ei, long long E,
                                             int* gcnt, unsigned* binned, int B) {
    __shared__ int cursor[512];
    __shared__ int delta[512];
    __shared__ int wsum[8];
    __shared__ int s_total;
    __shared__ unsigned sv[CHUNK];
    __shared__ unsigned short sb[CHUNK];
    __shared__ int s_nz;
    int t = threadIdx.x, blk = blockIdx.x;
    if (t == 0) s_nz = 0;
    cursor[t] = 0;
    __syncthreads();
    int f = detect64((const unsigned*)ei, &s_nz, t);
    long long s = (long long)blk * CHUNK, e = min(E, s + CHUNK);
    // ---- single global read: pack edges into register slots ----
    // slot 2k   <- edge at i = s + 2t + k*1024      (valid iff i   < e)
    // slot 2k+1 <- edge at i+1                       (valid iff i+1 < e)
    unsigned pv[14];
    unsigned short pbk[14];
    if (f) {
        const long long* p = (const long long*)ei;
#pragma unroll
        for (int k = 0; k < 7; k++) {
            long long i = s + 2 * t + (long long)k * 1024;
            if (i + 1 < e) {
                longlong2 sp = *(const longlong2*)(p + i);
                longlong2 dp = *(const longlong2*)(p + E + i);
                pv[2 * k] = ((unsigned)(int)sp.x << 9) | (unsigned)((int)dp.x & 511);
                pbk[2 * k] = (unsigned short)(((int)dp.x) >> 9);
                pv[2 * k + 1] = ((unsigned)(int)sp.y << 9) | (unsigned)((int)dp.y & 511);
                pbk[2 * k + 1] = (unsigned short)(((int)dp.y) >> 9);
            } else if (i < e) {
                int sval = (int)p[i], dv = (int)p[E + i];
                pv[2 * k] = ((unsigned)sval << 9) | (unsigned)(dv & 511);
                pbk[2 * k] = (unsigned short)(dv >> 9);
            }
        }
    } else {
        const int* p = (const int*)ei;
#pragma unroll
        for (int k = 0; k < 7; k++) {
            long long i = s + 2 * t + (long long)k * 1024;
            if (i + 1 < e) {
                int2 sp = *(const int2*)(p + i);
                int2 dp = *(const int2*)(p + E + i);
                pv[2 * k] = ((unsigned)sp.x << 9) | (unsigned)(dp.x & 511);
                pbk[2 * k] = (unsigned short)(dp.x >> 9);
                pv[2 * k + 1] = ((unsigned)sp.y << 9) | (unsigned)(dp.y & 511);
                pbk[2 * k + 1] = (unsigned short)(dp.y >> 9);
            } else if (i < e) {
                int sval = p[i], dv = p[E + i];
                pv[2 * k] = ((unsigned)sval << 9) | (unsigned)(dv & 511);
                pbk[2 * k] = (unsigned short)(dv >> 9);
            }
        }
    }
    // ---- histogram from registers ----
#pragma unroll
    for (int k = 0; k < 14; k++) {
        long long i = s + 2 * t + (long long)(k >> 1) * 1024 + (k & 1);
        if (i < e) atomicAdd(&cursor[pbk[k]], 1);
    }
    __syncthreads();
    // exclusive scan over 512 counts: wave shuffle scan + cross-wave offsets
    int c = cursor[t];
    int lane = t & 63, wid = t >> 6;
    int inc = c;
#pragma unroll
    for (int off = 1; off < 64; off <<= 1) {
        int up = __shfl_up(inc, off, 64);
        if (lane >= off) inc += up;
    }
    if (lane == 63) wsum[wid] = inc;
    __syncthreads();
    int base = 0;
    for (int k = 0; k < wid; k++) base += wsum[k];
    int ex = base + inc - c;
    if (t == 511) s_total = ex + c;
    int claim = c ? atomicAdd(&gcnt[t], c) : 0;
    delta[t] = t * CAP + claim - ex;
    cursor[t] = ex;
    __syncthreads();
    // ---- scatter into LDS from registers ----
#pragma unroll
    for (int k = 0; k < 14; k++) {
        long long i = s + 2 * t + (long long)(k >> 1) * 1024 + (k & 1);
        if (i < e) {
            int pos = atomicAdd(&cursor[pbk[k]], 1);
            sv[pos] = pv[k];
            sb[pos] = pbk[k];
        }
    }
    __syncthreads();
    // linear copy-out (consecutive threads -> consecutive addresses)
    int total = s_total;
    for (int i = t; i < total; i += 512)
        binned[delta[sb[i]] + i] = sv[i];
}

// Per-bucket counting sort by local node, scattering csr DIRECTLY to the
// block-owned global region. 1024 threads; shuffle scan over 512 counters.
// Also iptr2, dinv, p1 = x*dinv.
__global__ __launch_bounds__(1024) void k_bucket_csr(
        const unsigned* binned, const int* gcnt, const float* x, int2* iptr2,
        float* dinv, float2* p1, int* csr, int n) {
    __shared__ int cur[512];
    __shared__ int wsum[16];
    int t = threadIdx.x, b = blockIdx.x;
    if (t < 512) cur[t] = 0;
    __syncthreads();
    int cnt = gcnt[b];
    const unsigned* bp = binned + (size_t)b * CAP;
    for (int i = t; i < cnt; i += 1024)
        atomicAdd(&cur[bp[i] & 511u], 1);
    __syncthreads();
    int c = (t < 512) ? cur[t] : 0;
    int lane = t & 63, wid = t >> 6;
    int inc = c;
#pragma unroll
    for (int off = 1; off < 64; off <<= 1) {
        int up = __shfl_up(inc, off, 64);
        if (lane >= off) inc += up;
    }
    if (lane == 63) wsum[wid] = inc;
    __syncthreads();
    int base = 0;
    for (int k = 0; k < wid; k++) base += wsum[k];
    int ex = base + inc - c;
    int gbase = b * CAP;
    if (t < 512) {
        cur[t] = gbase + ex;  // global cursor
        int node = b * 512 + t;
        if (node < n) {
            iptr2[node] = make_int2(gbase + ex, gbase + ex + c);
            float dg = (float)(c + 1);  // +1 self loop
            float r = rsqrtf(dg);
            r = r * (1.5f - 0.5f * dg * r * r);  // Newton refine
            dinv[node] = r;
            p1[node] = make_float2(x[2 * node] * r, x[2 * node + 1] * r);
        }
    }
    __syncthreads();
    for (int i = t; i < cnt; i += 1024) {
        unsigned p = bp[i];
        int pos = atomicAdd(&cur[p & 511u], 1);
        csr[pos] = (int)(p >> 9);
    }
}

// Fused: aggx = A_hat x (dim2, x8 unroll, fp32 pairwise-tree acc);
// t4 = (ax, ay, dinv, 0) -- the 16B generator of this node's h-row.
__global__ void k_agg2_l1(const float2* p1, const int2* iptr2, const int* csr,
                          const float* dinv, float4* t4, int n) {
    int v = blockIdx.x * 256 + threadIdx.x;
    if (v >= n) return;
    float2 a0 = p1[v];
    float dax = a0.x, day = a0.y;
    int2 se = iptr2[v];
    int s = se.x, e = se.y;
    int i = s;
    for (; i + 7 < e; i += 8) {
        int u0 = csr[i], u1 = csr[i + 1], u2 = csr[i + 2], u3 = csr[i + 3];
        int u4 = csr[i + 4], u5 = csr[i + 5], u6 = csr[i + 6], u7 = csr[i + 7];
        float2 q0 = p1[u0], q1 = p1[u1], q2 = p1[u2], q3 = p1[u3];
        float2 q4 = p1[u4], q5 = p1[u5], q6 = p1[u6], q7 = p1[u7];
        dax += ((q0.x + q1.x) + (q2.x + q3.x)) + ((q4.x + q5.x) + (q6.x + q7.x));
        day += ((q0.y + q1.y) + (q2.y + q3.y)) + ((q4.y + q5.y) + (q6.y + q7.y));
    }
    for (; i < e; i++) {
        float2 q = p1[csr[i]];
        dax += q.x; day += q.y;
    }
    float r = dinv[v];
    float ax = dax * r, ay = day * r;
    t4[v] = make_float4(ax, ay, r, 0.f);
}

// Dim-30 aggregation by RECOMPUTE: 8-lane group per node; each lane owns
// dims 4l..4l+3 (W1 columns in registers). Per neighbor: one broadcast 16B
// float4 gather from the 3.2MB t4 table (L2-resident), then
// h_j = relu(ax*W1[j] + ay*W1[30+j] + b1[j]) recomputed in fp32 and
// accumulated scaled via a single fma: acc_j += h_j * r_u. 4 instr/dim.
__global__ void k_agg30(const float4* t4, const int2* iptr2, const int* csr,
                        const float* W1, const float* b1,
                        uint2* agghu, int n) {
    int t = threadIdx.x;
    int g = blockIdx.x * 32 + (t >> 3);
    int l = t & 7;
    if (g >= n) return;
    float w0[4], w1[4], bb[4];
#pragma unroll
    for (int k = 0; k < 4; k++) {
        int j = 4 * l + k;
        bool ok = (j < 30);
        w0[k] = ok ? W1[j] : 0.f;
        w1[k] = ok ? W1[30 + j] : 0.f;
        bb[k] = ok ? b1[j] : 0.f;
    }
    float4 qs = t4[g];  // self
    float a0 = fmaxf(fmaf(qs.x, w0[0], fmaf(qs.y, w1[0], bb[0])), 0.f) * qs.z;
    float a1 = fmaxf(fmaf(qs.x, w0[1], fmaf(qs.y, w1[1], bb[1])), 0.f) * qs.z;
    float a2 = fmaxf(fmaf(qs.x, w0[2], fmaf(qs.y, w1[2], bb[2])), 0.f) * qs.z;
    float a3 = fmaxf(fmaf(qs.x, w0[3], fmaf(qs.y, w1[3], bb[3])), 0.f) * qs.z;
#define DIM4(q)                                                                    \
    {                                                                              \
        a0 = fmaf(fmaxf(fmaf(q.x, w0[0], fmaf(q.y, w1[0], bb[0])), 0.f), q.z, a0); \
        a1 = fmaf(fmaxf(fmaf(q.x, w0[1], fmaf(q.y, w1[1], bb[1])), 0.f), q.z, a1); \
        a2 = fmaf(fmaxf(fmaf(q.x, w0[2], fmaf(q.y, w1[2], bb[2])), 0.f), q.z, a2); \
        a3 = fmaf(fmaxf(fmaf(q.x, w0[3], fmaf(q.y, w1[3], bb[3])), 0.f), q.z, a3); \
    }
    int2 se = iptr2[g];
    int s = se.x, e = se.y;
    int i = s;
    for (; i + 3 < e; i += 4) {
        int u0 = csr[i], u1 = csr[i + 1], u2 = csr[i + 2], u3 = csr[i + 3];
        float4 q0 = t4[u0], q1 = t4[u1], q2 = t4[u2], q3 = t4[u3];
        DIM4(q0); DIM4(q1); DIM4(q2); DIM4(q3);
    }
    for (; i < e; i++) {
        float4 q = t4[csr[i]];
        DIM4(q);
    }
#undef DIM4
    float r = qs.z;
    uint2 o;
    o.x = (unsigned)f2bf(a0 * r) | ((unsigned)f2bf(a1 * r) << 16);
    o.y = (unsigned)f2bf(a2 * r) | ((unsigned)f2bf(a3 * r) << 16);
    agghu[(size_t)g * 8 + l] = o;  // pads (cols 30,31) are zero -> stay 0
}

// h2 = relu((Ah1)W2[:30] + (Ax)W2[30:] + b2); p3 = ([h2,x]@W3) * dinv.
// Block stages its 256 bf16 aggh rows through LDS (stride-17 uints).
// Reads t4 for (ax, ay, dinv).
__global__ void k_layer2(const unsigned short* aggh, const float4* t4,
                         const float* x, const float* W2, const float* W3,
                         const float* b2, float* p3, int n) {
    __shared__ float W2s[32 * 30];
    __shared__ float W3s[32];
    __shared__ float b2s[30];
    __shared__ unsigned hsh[256 * 17];
    int t = threadIdx.x;
    for (int i = t; i < 960; i += 256) W2s[i] = W2[i];
    if (t < 32) W3s[t] = W3[t];
    if (t < 30) b2s[t] = b2[t];
    const unsigned* ag = (const unsigned*)aggh + (size_t)blockIdx.x * 256 * 16;
    int rows = min(256, n - blockIdx.x * 256);
    for (int i = t; i < rows * 16; i += 256) {
        int rr = i >> 4, cc = i & 15;
        hsh[rr * 17 + cc] = ag[i];
    }
    __syncthreads();
    int v = blockIdx.x * 256 + t;
    if (v >= n) return;
    float4 a = t4[v];
    float acc[30];
#pragma unroll
    for (int j = 0; j < 30; j++)
        acc[j] = fmaf(a.x, W2s[30 * 30 + j], fmaf(a.y, W2s[31 * 30 + j], b2s[j]));
#pragma unroll
    for (int kk = 0; kk < 15; kk++) {  // 30 values = 15 uint pairs
        unsigned pr = hsh[t * 17 + kk];
        float h0 = bf2f((unsigned short)(pr & 0xFFFFu));
        float h1v = bf2f((unsigned short)(pr >> 16));
#pragma unroll
        for (int j = 0; j < 30; j++)
            acc[j] = fmaf(h0, W2s[(2 * kk) * 30 + j], acc[j]);
#pragma unroll
        for (int j = 0; j < 30; j++)
            acc[j] = fmaf(h1v, W2s[(2 * kk + 1) * 30 + j], acc[j]);
    }
    float s3 = 0.f;
#pragma unroll
    for (int j = 0; j < 30; j++) s3 = fmaf(fmaxf(acc[j], 0.f), W3s[j], s3);
    s3 = fmaf(x[2 * v], W3s[30], s3);
    s3 = fmaf(x[2 * v + 1], W3s[31], s3);
    p3[v] = s3 * a.z;
}

// out_v = dinv_v * (p3_v + sum p3_u) + b3   (dim 1, x8 unroll, fp32 tree acc)
__global__ void k_agg1(const float* p3, const int2* iptr2, const int* csr,
                       const float* dinv, const float* b3, float* out, int n) {
    int v = blockIdx.x * 256 + threadIdx.x;
    if (v >= n) return;
    float acc = p3[v];
    int2 se = iptr2[v];
    int s = se.x, e = se.y;
    int i = s;
    for (; i + 7 < e; i += 8) {
        int u0 = csr[i], u1 = csr[i + 1], u2 = csr[i + 2], u3 = csr[i + 3];
        int u4 = csr[i + 4], u5 = csr[i + 5], u6 = csr[i + 6], u7 = csr[i + 7];
        float f0 = p3[u0], f1 = p3[u1], f2 = p3[u2], f3 = p3[u3];
        float f4 = p3[u4], f5 = p3[u5], f6 = p3[u6], f7 = p3[u7];
        acc += ((f0 + f1) + (f2 + f3)) + ((f4 + f5) + (f6 + f7));
    }
    for (; i < e; i++) acc += p3[csr[i]];
    out[v] = fmaf(acc, dinv[v], b3[0]);
}

extern "C" void kernel_launch(void* const* d_in, const int* in_sizes, int n_in,
                              void* d_out, int out_size, void* d_ws, size_t ws_size,
                              hipStream_t stream) {
    const float* x  = (const float*)d_in[0];
    const void*  ei = d_in[1];
    const float* W1 = (const float*)d_in[2];
    const float* b1 = (const float*)d_in[3];
    const float* W2 = (const float*)d_in[4];
    const float* b2 = (const float*)d_in[5];
    const float* W3 = (const float*)d_in[6];
    const float* b3 = (const float*)d_in[7];
    float* out = (float*)d_out;
    const int n = in_sizes[0] / 2;
    const long long E = in_sizes[1] / 2;
    const int B = (n + 511) / 512;  // dst buckets of 512 nodes (<=512 buckets)

    char* w = (char*)d_ws;
    auto alloc = [&](size_t b) { void* p = (void*)w; w += (b + 255) & ~(size_t)255; return p; };
    int*            gcnt   = (int*)alloc(512 * 4);
    unsigned*       binned = (unsigned*)alloc((size_t)B * CAP * 4);
    int*            csr    = (int*)alloc((size_t)B * CAP * 4);
    int2*           iptr2  = (int2*)alloc((size_t)n * 8);
    float*          dinv   = (float*)alloc((size_t)n * 4);
    float2*         p1     = (float2*)alloc((size_t)n * 8);
    float4*         t4     = (float4*)alloc((size_t)n * 16);
    unsigned short* aggh   = (unsigned short*)alloc((size_t)n * 32 * 2);
    float*          p3     = (float*)alloc((size_t)n * 4);

    int nblocks = (n + 255) / 256;
    int nbin = (int)((E + CHUNK - 1) / CHUNK);

    hipMemsetAsync(gcnt, 0, 512 * 4, stream);
    k_bin<<<nbin, 512, 0, stream>>>(ei, E, gcnt, binned, B);
    k_bucket_csr<<<B, 1024, 0, stream>>>(binned, gcnt, x, iptr2, dinv, p1, csr, n);
    k_agg2_l1<<<nblocks, 256, 0, stream>>>(p1, iptr2, csr, dinv, t4, n);
    k_agg30<<<(n + 31) / 32, 256, 0, stream>>>(t4, iptr2, csr, W1, b1,
                                               (uint2*)aggh, n);
    k_layer2<<<nblocks, 256, 0, stream>>>(aggh, t4, x, W2, W3, b2, p3, n);
    k_agg1<<<nblocks, 256, 0, stream>>>(p3, iptr2, csr, dinv, b3, out, n);
}